// Round 1
// baseline (5985.010 us; speedup 1.0000x reference)
//
#include <hip/hip_runtime.h>
#include <cstddef>

// ---------------- problem dims ----------------
#define NF    1024
#define NSEQ  4096
#define NB    4
#define NROWS (NB*NSEQ)      // 16384
#define NADA  6144
#define NHID  4096
#define NST   64
#define NCH   128            // dir(2) * state(64) complex channels
#define LCH   64             // scan chunk length
#define NCHUNK (NSEQ/LCH)    // 64
#define MLP_ROWS 2048
#define NMLP  (NROWS/MLP_ROWS)

// ---------------- tiled fp32 GEMM core: 64x64 tile, BK=16, 256 thr, 4x4/thr ----
#define BM 64
#define BN 64
#define BK 16

__device__ __forceinline__ void gemm_core(
    const float* __restrict__ A, int lda,      // A[M][lda], row-major
    const float* __restrict__ B, int ldb,      // B[K][ldb], row-major
    int K, int row0, int col0, float acc[4][4], float* sm)
{
  float* As = sm;            // [BK][BM] k-major
  float* Bs = sm + BK*BM;    // [BK][BN]
  const int tid = threadIdx.x;
  const int tx = tid & 15, ty = tid >> 4;
  const int am = tid >> 2, akq = (tid & 3) << 2;
  const int bk = tid >> 4, bnq = (tid & 15) << 2;
  for (int k0 = 0; k0 < K; k0 += BK) {
    float4 a4 = *(const float4*)(A + (size_t)(row0 + am)*lda + (k0 + akq));
    As[(akq+0)*BM + am] = a4.x;
    As[(akq+1)*BM + am] = a4.y;
    As[(akq+2)*BM + am] = a4.z;
    As[(akq+3)*BM + am] = a4.w;
    *(float4*)(Bs + bk*BN + bnq) = *(const float4*)(B + (size_t)(k0 + bk)*ldb + col0 + bnq);
    __syncthreads();
#pragma unroll
    for (int k = 0; k < BK; ++k) {
      float4 av = *(const float4*)(As + k*BM + (ty<<2));
      float4 bv = *(const float4*)(Bs + k*BN + (tx<<2));
      float a[4] = {av.x, av.y, av.z, av.w};
      float b[4] = {bv.x, bv.y, bv.z, bv.w};
#pragma unroll
      for (int i = 0; i < 4; ++i)
#pragma unroll
        for (int j = 0; j < 4; ++j)
          acc[i][j] += a[i]*b[j];
    }
    __syncthreads();
  }
}

__device__ __forceinline__ float gelu_tanh(float x) {
  float x3 = x*x*x;
  float u = 0.7978845608028654f*(x + 0.044715f*x3);
  return 0.5f*x*(1.f + tanhf(u));
}

// ---------------- small kernels ----------------
__global__ __launch_bounds__(256) void k_silu(const float* __restrict__ cond, float* __restrict__ sc) {
  int id = blockIdx.x*256 + threadIdx.x;
  if (id < NB*NF) { float c = cond[id]; sc[id] = c / (1.f + expf(-c)); }
}

__global__ __launch_bounds__(256) void k_ada(const float* __restrict__ sc, const float* __restrict__ adaW,
                                             const float* __restrict__ adab, float* __restrict__ ada) {
  int j = blockIdx.x*256 + threadIdx.x;   // 0..6143
  int b = blockIdx.y;
  float acc = adab[j];
  const float* s = sc + b*NF;
  for (int k = 0; k < NF; ++k) acc += s[k] * adaW[(size_t)k*NADA + j];
  ada[(size_t)b*NADA + j] = acc;
}

// per-direction S5 discretization tables
__global__ __launch_bounds__(64) void k_param(
    const float* __restrict__ lAf, const float* __restrict__ Aif, const float* __restrict__ ldtf,
    const float* __restrict__ lAb, const float* __restrict__ Aib, const float* __restrict__ ldtb,
    float* __restrict__ Abar, float* __restrict__ coef, float* __restrict__ AbarL, float* __restrict__ Apow)
{
  int d = blockIdx.x, n = threadIdx.x;
  const float* lA  = d ? lAb  : lAf;
  const float* Ai  = d ? Aib  : Aif;
  const float* ldt = d ? ldtb : ldtf;
  float dt  = expf(ldt[n]);
  float Are = -expf(lA[n]);
  float Aim = Ai[n];
  float ar = Are*dt, ai = Aim*dt;
  float m = expf(ar);
  float Abr = m*cosf(ai), Abi = m*sinf(ai);
  int t = d*NST + n;
  Abar[2*t] = Abr; Abar[2*t+1] = Abi;
  // coef = (Abar - 1)/(A_diag + 1e-8)
  float cr = Abr - 1.f, ci = Abi;
  float dr = Are + 1e-8f, di = Aim;
  float den = dr*dr + di*di;
  coef[2*t]   = (cr*dr + ci*di)/den;
  coef[2*t+1] = (ci*dr - cr*di)/den;
  for (int j = 0; j < LCH; ++j) {            // Apow[j] = Abar^(j+1)
    float p = (float)(j+1);
    float mp = expf(ar*p);
    Apow[(size_t)(t*LCH + j)*2 + 0] = mp*cosf(ai*p);
    Apow[(size_t)(t*LCH + j)*2 + 1] = mp*sinf(ai*p);
  }
  float mL = expf(ar*64.f);
  AbarL[2*t] = mL*cosf(ai*64.f); AbarL[2*t+1] = mL*sinf(ai*64.f);
}

// Bmat[f][2c+p] : complexified B_bar for one fused Bu GEMM (both dirs)
__global__ __launch_bounds__(256) void k_bmat(
    const float* __restrict__ Brf, const float* __restrict__ Bif,
    const float* __restrict__ Brb, const float* __restrict__ Bib,
    const float* __restrict__ coef, float* __restrict__ Bmat)
{
  int id = blockIdx.x*256 + threadIdx.x;     // < NF*NCH
  int c = id & (NCH-1), f = id >> 7;
  int d = c >> 6, n = c & 63;
  const float* Br = d ? Brb : Brf;
  const float* Bi = d ? Bib : Bif;
  float br = Br[(size_t)n*NF + f], bi = Bi[(size_t)n*NF + f];
  float crr = coef[2*c], cii = coef[2*c+1];
  Bmat[(size_t)f*(2*NCH) + 2*c]   = crr*br - cii*bi;
  Bmat[(size_t)f*(2*NCH) + 2*c+1] = crr*bi + cii*br;
}

// LayerNorm (no affine) + AdaLN modulate
__global__ __launch_bounds__(256) void k_ln_mod(const float* __restrict__ xin, const float* __restrict__ ada,
                                                int sh_off, int sc_off, float* __restrict__ outp) {
  const int row = blockIdx.x;
  const int b = row >> 12;
  const int tid = threadIdx.x;
  float4 v = ((const float4*)(xin + (size_t)row*NF))[tid];
  float s1 = v.x+v.y+v.z+v.w;
  float s2 = v.x*v.x + v.y*v.y + v.z*v.z + v.w*v.w;
  for (int off = 32; off > 0; off >>= 1) { s1 += __shfl_down(s1, off); s2 += __shfl_down(s2, off); }
  __shared__ float r1[4], r2[4];
  if ((tid & 63) == 0) { r1[tid>>6] = s1; r2[tid>>6] = s2; }
  __syncthreads();
  float S1 = r1[0]+r1[1]+r1[2]+r1[3];
  float S2 = r2[0]+r2[1]+r2[2]+r2[3];
  float mean = S1 * (1.0f/NF);
  float var  = S2 * (1.0f/NF) - mean*mean;
  float inv  = rsqrtf(var + 1e-5f);
  const float* arow = ada + (size_t)b*NADA;
  int f = tid << 2;
  float4 r;
  r.x = (v.x - mean)*inv*(1.f + arow[sc_off + f+0]) + arow[sh_off + f+0];
  r.y = (v.y - mean)*inv*(1.f + arow[sc_off + f+1]) + arow[sh_off + f+1];
  r.z = (v.z - mean)*inv*(1.f + arow[sc_off + f+2]) + arow[sh_off + f+2];
  r.w = (v.w - mean)*inv*(1.f + arow[sc_off + f+3]) + arow[sh_off + f+3];
  ((float4*)(outp + (size_t)row*NF))[tid] = r;
}

// Bu GEMM: [16384,1024] @ [1024,256] -> BuAll[16384][256] (re/im interleaved per channel)
__global__ __launch_bounds__(256) void k_gemm_bu(const float* __restrict__ A, const float* __restrict__ B,
                                                 float* __restrict__ C) {
  __shared__ float sm[2*BK*BM];
  float acc[4][4] = {};
  int row0 = blockIdx.x*BM, col0 = blockIdx.y*BN;
  gemm_core(A, NF, B, 2*NCH, NF, row0, col0, acc, sm);
  int tx = threadIdx.x & 15, ty = threadIdx.x >> 4;
#pragma unroll
  for (int i = 0; i < 4; ++i) {
    size_t r = row0 + (ty<<2) + i;
    *(float4*)(C + r*(2*NCH) + col0 + (tx<<2)) = make_float4(acc[i][0], acc[i][1], acc[i][2], acc[i][3]);
  }
}

// scan phase A: per-(b,chunk) local complex scan; fwd (t<64) ascending s, bwd descending
__global__ __launch_bounds__(128) void k_scanA(float* __restrict__ Bu, const float* __restrict__ Abar,
                                               float* __restrict__ P) {
  int t = threadIdx.x;               // channel
  int bc = blockIdx.x;               // b*64 + chunk
  int b = bc >> 6, c = bc & 63;
  int d = t >> 6;
  float2 A = ((const float2*)Abar)[t];
  float sr = 0.f, si = 0.f;
  size_t base = ((size_t)b*NSEQ)*(2*NCH);
  for (int j = 0; j < LCH; ++j) {
    int s = d ? (c*LCH + (LCH-1) - j) : (c*LCH + j);
    float2* p = (float2*)(Bu + base + (size_t)s*(2*NCH)) + t;
    float2 u = *p;
    float nr = A.x*sr - A.y*si + u.x;
    float ni = A.x*si + A.y*sr + u.y;
    sr = nr; si = ni;
    *p = make_float2(sr, si);
  }
  ((float2*)P)[(size_t)bc*NCH + t] = make_float2(sr, si);
}

// scan phase B: sequential combine of chunk carries (64 steps); 4 batches x 128 channels
__global__ __launch_bounds__(512) void k_scanB(const float* __restrict__ P, const float* __restrict__ AbarL,
                                               float* __restrict__ carry) {
  int t = threadIdx.x & (NCH-1);
  int b = threadIdx.x >> 7;
  int d = t >> 6;
  float2 AL = ((const float2*)AbarL)[t];
  float sr = 0.f, si = 0.f;
  if (d == 0) {
    for (int c = 0; c < NCHUNK; ++c) {
      ((float2*)carry)[((size_t)b*NCHUNK + c)*NCH + t] = make_float2(sr, si);
      float2 p = ((const float2*)P)[((size_t)b*NCHUNK + c)*NCH + t];
      float nr = AL.x*sr - AL.y*si + p.x;
      float ni = AL.x*si + AL.y*sr + p.y;
      sr = nr; si = ni;
    }
  } else {
    for (int c = NCHUNK-1; c >= 0; --c) {
      ((float2*)carry)[((size_t)b*NCHUNK + c)*NCH + t] = make_float2(sr, si);
      float2 p = ((const float2*)P)[((size_t)b*NCHUNK + c)*NCH + t];
      float nr = AL.x*sr - AL.y*si + p.x;
      float ni = AL.x*si + AL.y*sr + p.y;
      sr = nr; si = ni;
    }
  }
}

// scan phase C: xs = local + Abar^(tau+1) * carry
__global__ __launch_bounds__(128) void k_scanC(float* __restrict__ Bu, const float* __restrict__ Apow,
                                               const float* __restrict__ carry) {
  int t = threadIdx.x;
  int bc = blockIdx.x;
  int b = bc >> 6, c = bc & 63;
  int d = t >> 6;
  float2 E = ((const float2*)carry)[(size_t)bc*NCH + t];
  const float2* Ap = ((const float2*)Apow) + (size_t)t*LCH;
  size_t base = ((size_t)b*NSEQ)*(2*NCH);
  for (int j = 0; j < LCH; ++j) {
    int s = c*LCH + j;
    int tau = d ? (LCH-1 - j) : j;
    float2 ap = Ap[tau];
    float2* p = (float2*)(Bu + base + (size_t)s*(2*NCH)) + t;
    float2 v = *p;
    v.x += ap.x*E.x - ap.y*E.y;
    v.y += ap.x*E.y + ap.y*E.x;
    *p = v;
  }
}

// G[r][fo] = sign * sum_f C_{re/im,d}[f,n] * out_W[d*1024+f][fo]   (r = 2*(d*64+n)+{0,1})
__global__ __launch_bounds__(256) void k_g(
    const float* __restrict__ Crf, const float* __restrict__ Cif,
    const float* __restrict__ Crb, const float* __restrict__ Cib,
    const float* __restrict__ W, float* __restrict__ G)
{
  int g = blockIdx.x;                // 0..31, 8 r's per block
  int tid = threadIdx.x;
  int d = g >> 4;
  const float* Cr = d ? Crb : Crf;
  const float* Ci = d ? Cib : Cif;
  const float* Wd = W + (size_t)d*NF*NF;
  float4 acc[8];
#pragma unroll
  for (int rr = 0; rr < 8; ++rr) acc[rr] = make_float4(0.f,0.f,0.f,0.f);
  int c4 = tid << 2;
  for (int k = 0; k < NF; ++k) {
    float4 w = *(const float4*)(Wd + (size_t)k*NF + c4);
#pragma unroll
    for (int rr = 0; rr < 8; ++rr) {
      int n = (g*4 + (rr>>1)) & 63;
      float s = (rr & 1) ? Ci[(size_t)k*NST + n] : Cr[(size_t)k*NST + n];
      acc[rr].x += s*w.x; acc[rr].y += s*w.y; acc[rr].z += s*w.z; acc[rr].w += s*w.w;
    }
  }
#pragma unroll
  for (int rr = 0; rr < 8; ++rr) {
    int r = g*8 + rr;
    float sgn = (rr & 1) ? -1.f : 1.f;
    *(float4*)(G + (size_t)r*NF + c4) =
        make_float4(sgn*acc[rr].x, sgn*acc[rr].y, sgn*acc[rr].z, sgn*acc[rr].w);
  }
}

// W_D[f][fo] = D_f[f]*W_top[f][fo] + D_b[f]*W_bot[f][fo]
__global__ __launch_bounds__(256) void k_wd(const float* __restrict__ Df, const float* __restrict__ Db,
                                            const float* __restrict__ W, float* __restrict__ WD) {
  int id = blockIdx.x*256 + threadIdx.x;
  int fo = id & (NF-1); int f = id >> 10;
  WD[id] = Df[f]*W[(size_t)f*NF + fo] + Db[f]*W[(size_t)(NF+f)*NF + fo];
}

// x1 = x + g1 * ( xs@G + h@W_D + out_b )
__global__ __launch_bounds__(256) void k_gemm_x1(
    const float* __restrict__ xs, const float* __restrict__ G,
    const float* __restrict__ h, const float* __restrict__ WD,
    const float* __restrict__ x, const float* __restrict__ ada,
    const float* __restrict__ outb, float* __restrict__ outp)
{
  __shared__ float sm[2*BK*BM];
  float acc[4][4] = {};
  int row0 = blockIdx.x*BM, col0 = blockIdx.y*BN;
  gemm_core(xs, 2*NCH, G, NF, 2*NCH, row0, col0, acc, sm);
  gemm_core(h, NF, WD, NF, NF, row0, col0, acc, sm);
  int tx = threadIdx.x & 15, ty = threadIdx.x >> 4;
  int b = row0 >> 12;
  const float* g1 = ada + (size_t)b*NADA + 2*NF;
#pragma unroll
  for (int i = 0; i < 4; ++i) {
    size_t r = row0 + (ty<<2) + i;
    int c = col0 + (tx<<2);
    float4 xv = *(const float4*)(x + r*NF + c);
    float4 v;
    v.x = xv.x + g1[c+0]*(acc[i][0] + outb[c+0]);
    v.y = xv.y + g1[c+1]*(acc[i][1] + outb[c+1]);
    v.z = xv.z + g1[c+2]*(acc[i][2] + outb[c+2]);
    v.w = xv.w + g1[c+3]*(acc[i][3] + outb[c+3]);
    *(float4*)(outp + r*NF + c) = v;
  }
}

// mid = gelu(h2@W1 + b1)   (one MLP row-chunk)
__global__ __launch_bounds__(256) void k_gemm_mlp1(const float* __restrict__ h2, const float* __restrict__ W1,
                                                   const float* __restrict__ b1, float* __restrict__ mid, int ch) {
  __shared__ float sm[2*BK*BM];
  float acc[4][4] = {};
  int row0 = blockIdx.x*BM, col0 = blockIdx.y*BN;
  const float* A = h2 + (size_t)ch*MLP_ROWS*NF;
  gemm_core(A, NF, W1, NHID, NF, row0, col0, acc, sm);
  int tx = threadIdx.x & 15, ty = threadIdx.x >> 4;
#pragma unroll
  for (int i = 0; i < 4; ++i) {
    size_t r = row0 + (ty<<2) + i;
    int c = col0 + (tx<<2);
    float4 v;
    v.x = gelu_tanh(acc[i][0] + b1[c+0]);
    v.y = gelu_tanh(acc[i][1] + b1[c+1]);
    v.z = gelu_tanh(acc[i][2] + b1[c+2]);
    v.w = gelu_tanh(acc[i][3] + b1[c+3]);
    *(float4*)(mid + r*NHID + c) = v;
  }
}

// out = x1 + g2 * (mid@W2 + b2)   (in-place on d_out)
__global__ __launch_bounds__(256) void k_gemm_mlp2(const float* __restrict__ mid, const float* __restrict__ W2,
                                                   const float* __restrict__ b2, const float* __restrict__ ada,
                                                   float* __restrict__ outp, int ch) {
  __shared__ float sm[2*BK*BM];
  float acc[4][4] = {};
  int row0 = blockIdx.x*BM, col0 = blockIdx.y*BN;
  gemm_core(mid, NHID, W2, NF, NHID, row0, col0, acc, sm);
  int tx = threadIdx.x & 15, ty = threadIdx.x >> 4;
#pragma unroll
  for (int i = 0; i < 4; ++i) {
    size_t r = (size_t)ch*MLP_ROWS + row0 + (ty<<2) + i;
    int b = (int)(r >> 12);
    const float* g2 = ada + (size_t)b*NADA + 5*NF;
    int c = col0 + (tx<<2);
    float4 o = *(float4*)(outp + r*NF + c);
    o.x += g2[c+0]*(acc[i][0] + b2[c+0]);
    o.y += g2[c+1]*(acc[i][1] + b2[c+1]);
    o.z += g2[c+2]*(acc[i][2] + b2[c+2]);
    o.w += g2[c+3]*(acc[i][3] + b2[c+3]);
    *(float4*)(outp + r*NF + c) = o;
  }
}

// ---------------- launcher ----------------
extern "C" void kernel_launch(void* const* d_in, const int* in_sizes, int n_in,
                              void* d_out, int out_size, void* d_ws, size_t ws_size,
                              hipStream_t stream) {
  // input-order hedge: dict order (out_W at 4) vs reference-signature order (fwd_log_A_real at 4)
  const bool sig = (in_sizes[4] == 64);
  const float* x    = (const float*)d_in[0];
  const float* cond = (const float*)d_in[1];
  const float* adaW = (const float*)d_in[2];
  const float* adab = (const float*)d_in[3];
  const int fwd0 = sig ? 4 : 11;
  const int bwd0 = sig ? 12 : 19;
  const float* outW = (const float*)d_in[sig ? 20 : 4];
  const float* outb = (const float*)d_in[sig ? 21 : 5];
  const float* W1   = (const float*)d_in[sig ? 22 : 6];
  const float* b1   = (const float*)d_in[sig ? 23 : 7];
  const float* W2   = (const float*)d_in[sig ? 24 : 8];
  const float* b2   = (const float*)d_in[sig ? 25 : 9];
  const float* lAf  = (const float*)d_in[fwd0+0];
  const float* Aif  = (const float*)d_in[fwd0+1];
  const float* Brf  = (const float*)d_in[fwd0+2];
  const float* Bif  = (const float*)d_in[fwd0+3];
  const float* Crf  = (const float*)d_in[fwd0+4];
  const float* Cif  = (const float*)d_in[fwd0+5];
  const float* Df   = (const float*)d_in[fwd0+6];
  const float* ldtf = (const float*)d_in[fwd0+7];
  const float* lAb  = (const float*)d_in[bwd0+0];
  const float* Aib  = (const float*)d_in[bwd0+1];
  const float* Brb  = (const float*)d_in[bwd0+2];
  const float* Bib  = (const float*)d_in[bwd0+3];
  const float* Crb  = (const float*)d_in[bwd0+4];
  const float* Cib  = (const float*)d_in[bwd0+5];
  const float* Db   = (const float*)d_in[bwd0+6];
  const float* ldtb = (const float*)d_in[bwd0+7];
  float* out = (float*)d_out;

  float* ws = (float*)d_ws;
  size_t o = 0;
  float* h     = ws + o; o += (size_t)NROWS*NF;         // 16.78M  (h, later reused for h2)
  float* bu    = ws + o; o += (size_t)NROWS*2*NCH;      // 4.19M   (Bu -> xs in place)
  float* mid   = ws + o; o += (size_t)MLP_ROWS*NHID;    // 8.39M
  float* ada   = ws + o; o += (size_t)NB*NADA;
  float* sc    = ws + o; o += (size_t)NB*NF;
  float* Bmat  = ws + o; o += (size_t)NF*2*NCH;
  float* G     = ws + o; o += (size_t)2*NCH*NF;
  float* WD    = ws + o; o += (size_t)NF*NF;
  float* Abar  = ws + o; o += 2*NCH;
  float* AbarL = ws + o; o += 2*NCH;
  float* coef  = ws + o; o += 2*NCH;
  float* Apow  = ws + o; o += (size_t)NCH*LCH*2;
  float* P     = ws + o; o += (size_t)NB*NCHUNK*NCH*2;
  float* carry = ws + o; o += (size_t)NB*NCHUNK*NCH*2;
  (void)ws_size; (void)n_in; (void)out_size;

  k_silu<<<(NB*NF+255)/256, 256, 0, stream>>>(cond, sc);
  k_ada<<<dim3(NADA/256, NB), 256, 0, stream>>>(sc, adaW, adab, ada);
  k_param<<<2, 64, 0, stream>>>(lAf, Aif, ldtf, lAb, Aib, ldtb, Abar, coef, AbarL, Apow);
  k_bmat<<<(NF*NCH)/256, 256, 0, stream>>>(Brf, Bif, Brb, Bib, coef, Bmat);
  k_ln_mod<<<NROWS, 256, 0, stream>>>(x, ada, 0, NF, h);
  k_gemm_bu<<<dim3(NROWS/BM, (2*NCH)/BN), 256, 0, stream>>>(h, Bmat, bu);
  k_scanA<<<NB*NCHUNK, NCH, 0, stream>>>(bu, Abar, P);
  k_scanB<<<1, 512, 0, stream>>>(P, AbarL, carry);
  k_scanC<<<NB*NCHUNK, NCH, 0, stream>>>(bu, Apow, carry);
  k_g<<<32, 256, 0, stream>>>(Crf, Cif, Crb, Cib, outW, G);
  k_wd<<<(NF*NF)/256, 256, 0, stream>>>(Df, Db, outW, WD);
  k_gemm_x1<<<dim3(NROWS/BM, NF/BN), 256, 0, stream>>>(bu, G, h, WD, x, ada, outb, out);
  k_ln_mod<<<NROWS, 256, 0, stream>>>(out, ada, 3*NF, 4*NF, h);   // h now holds h2
  for (int ch = 0; ch < NMLP; ++ch) {
    k_gemm_mlp1<<<dim3(MLP_ROWS/BM, NHID/BN), 256, 0, stream>>>(h, W1, b1, mid, ch);
    k_gemm_mlp2<<<dim3(MLP_ROWS/BM, NF/BN), 256, 0, stream>>>(mid, W2, b2, ada, out, ch);
  }
}

// Round 2
// 1354.397 us; speedup vs baseline: 4.4189x; 4.4189x over previous
//
#include <hip/hip_runtime.h>
#include <cstddef>

// ---------------- problem dims ----------------
#define NF    1024
#define NSEQ  4096
#define NB    4
#define NROWS (NB*NSEQ)      // 16384
#define NADA  6144
#define NHID  4096
#define NST   64
#define NCH   128            // dir(2) * state(64) complex channels
#define LCH   64             // scan chunk length
#define NCHUNK (NSEQ/LCH)    // 64
#define LDA   1280           // Acat leading dim (256 xs + 1024 h)
#define MLP_ROWS 4096
#define NMLP  (NROWS/MLP_ROWS)

typedef __bf16 bf16x8 __attribute__((ext_vector_type(8)));
typedef float f32x4 __attribute__((ext_vector_type(4)));

__device__ __forceinline__ unsigned short f2bf(float x) {
  union { float f; unsigned int u; } v; v.f = x;
  unsigned int r = v.u + 0x7fffu + ((v.u >> 16) & 1u);
  return (unsigned short)(r >> 16);
}

__device__ __forceinline__ float gelu_tanh(float x) {
  float x3 = x*x*x;
  float u = 0.7978845608028654f*(x + 0.044715f*x3);
  return 0.5f*x*(1.f + tanhf(u));
}

// ============ MFMA GEMM core: 128x128 tile, BK=32 bf16, 256 thr (4 waves) ===
// A row-major [M][lda], Bt row-major [N][ldb] (i.e. B transposed). m97 structure:
// global_load_lds width=16 staging, ds_read_b128 frags, 16x16x32 MFMA.
__device__ __forceinline__ void mfma_core(
    const unsigned short* __restrict__ A, int lda,
    const unsigned short* __restrict__ Bt, int ldb,
    int K, int row0, int col0, unsigned short* lds, f32x4 acc[4][4])
{
  const int tid  = threadIdx.x;
  const int wave = tid >> 6, lane = tid & 63;
  const int wm = wave & 1, wn = wave >> 1;
  const int sr = lane >> 2;            // staging row within 16-row group
  const int sc = (lane & 3) << 3;      // staging k-col (0,8,16,24)
  const int fr = lane & 15, fq = lane >> 4;
  unsigned short* sA = lds;            // [128][32]
  unsigned short* sB = lds + 128*32;   // [128][32]  (n-major)
  const unsigned short* a0 = A + (size_t)row0*lda;
  const unsigned short* b0 = Bt + (size_t)col0*ldb;
  for (int k0 = 0; k0 < K; k0 += 32) {
#pragma unroll
    for (int s = 0; s < 2; ++s) {
      int i = wave*2 + s;
      int r = i*16 + sr;
      __builtin_amdgcn_global_load_lds(
          (const __attribute__((address_space(1))) void*)(a0 + (size_t)r*lda + k0 + sc),
          (__attribute__((address_space(3))) void*)(sA + i*512), 16, 0, 0);
      __builtin_amdgcn_global_load_lds(
          (const __attribute__((address_space(1))) void*)(b0 + (size_t)r*ldb + k0 + sc),
          (__attribute__((address_space(3))) void*)(sB + i*512), 16, 0, 0);
    }
    __syncthreads();
    bf16x8 af[4], bv[4];
#pragma unroll
    for (int t = 0; t < 4; ++t) {
      af[t] = *(const bf16x8*)(sA + (wm*64 + t*16 + fr)*32 + fq*8);
      bv[t] = *(const bf16x8*)(sB + (wn*64 + t*16 + fr)*32 + fq*8);
    }
#pragma unroll
    for (int i = 0; i < 4; ++i)
#pragma unroll
      for (int j = 0; j < 4; ++j)
        acc[i][j] = __builtin_amdgcn_mfma_f32_16x16x32_bf16(af[i], bv[j], acc[i][j], 0, 0, 0);
    __syncthreads();
  }
}

// D mapping (m89-verified): col = n0 + (lane&15), row = m0 + (lane>>4)*4 + reg
#define EPI_LOOP(body) \
  { const int lane = threadIdx.x & 63, wave = threadIdx.x >> 6; \
    const int wm = wave & 1, wn = wave >> 1; \
    const int fr = lane & 15, fq = lane >> 4; \
    _Pragma("unroll") for (int i = 0; i < 4; ++i) \
    _Pragma("unroll") for (int j = 0; j < 4; ++j) \
    _Pragma("unroll") for (int r = 0; r < 4; ++r) { \
      int row = row0 + wm*64 + i*16 + fq*4 + r; \
      int col = col0 + wn*64 + j*16 + fr; \
      float aval = acc[i][j][r]; \
      body; } }

// Bu GEMM: h(bf16, Acat cols 256..) @ Bmat_t^T -> bu fp32 [16384][256]
__global__ __launch_bounds__(256) void k_mm_bu(const unsigned short* __restrict__ A,
                                               const unsigned short* __restrict__ Bt,
                                               float* __restrict__ C) {
  __shared__ __align__(16) unsigned short lds[2*128*32];
  f32x4 acc[4][4];
#pragma unroll
  for (int i = 0; i < 4; ++i)
#pragma unroll
    for (int j = 0; j < 4; ++j) acc[i][j] = (f32x4){0.f,0.f,0.f,0.f};
  int row0 = blockIdx.x*128, col0 = blockIdx.y*128;
  mfma_core(A, LDA, Bt, 1024, 1024, row0, col0, lds, acc);
  EPI_LOOP( C[(size_t)row*(2*NCH) + col] = aval; )
}

// proj: out = x + g1 * (Acat@Bcat^T + outb)
__global__ __launch_bounds__(256) void k_mm_proj(const unsigned short* __restrict__ A,
                                                 const unsigned short* __restrict__ Bt,
                                                 const float* __restrict__ x,
                                                 const float* __restrict__ ada,
                                                 const float* __restrict__ outb,
                                                 float* __restrict__ outp) {
  __shared__ __align__(16) unsigned short lds[2*128*32];
  f32x4 acc[4][4];
#pragma unroll
  for (int i = 0; i < 4; ++i)
#pragma unroll
    for (int j = 0; j < 4; ++j) acc[i][j] = (f32x4){0.f,0.f,0.f,0.f};
  int row0 = blockIdx.x*128, col0 = blockIdx.y*128;
  mfma_core(A, LDA, Bt, LDA, LDA, row0, col0, lds, acc);
  EPI_LOOP(
    const float* g1 = ada + (size_t)(row >> 12)*NADA + 2*NF;
    outp[(size_t)row*NF + col] = x[(size_t)row*NF + col] + g1[col]*(aval + outb[col]); )
}

// mlp1: mid = bf16(gelu(h2@W1t^T + b1))
__global__ __launch_bounds__(256) void k_mm_mlp1(const unsigned short* __restrict__ A,
                                                 const unsigned short* __restrict__ Bt,
                                                 const float* __restrict__ b1,
                                                 unsigned short* __restrict__ mid) {
  __shared__ __align__(16) unsigned short lds[2*128*32];
  f32x4 acc[4][4];
#pragma unroll
  for (int i = 0; i < 4; ++i)
#pragma unroll
    for (int j = 0; j < 4; ++j) acc[i][j] = (f32x4){0.f,0.f,0.f,0.f};
  int row0 = blockIdx.x*128, col0 = blockIdx.y*128;
  mfma_core(A, LDA, Bt, 1024, 1024, row0, col0, lds, acc);
  EPI_LOOP( mid[(size_t)row*NHID + col] = f2bf(gelu_tanh(aval + b1[col])); )
}

// mlp2: out += g2 * (mid@W2t^T + b2)
__global__ __launch_bounds__(256) void k_mm_mlp2(const unsigned short* __restrict__ A,
                                                 const unsigned short* __restrict__ Bt,
                                                 const float* __restrict__ b2,
                                                 const float* __restrict__ ada,
                                                 float* __restrict__ outp, int row_off) {
  __shared__ __align__(16) unsigned short lds[2*128*32];
  f32x4 acc[4][4];
#pragma unroll
  for (int i = 0; i < 4; ++i)
#pragma unroll
    for (int j = 0; j < 4; ++j) acc[i][j] = (f32x4){0.f,0.f,0.f,0.f};
  int row0 = blockIdx.x*128, col0 = blockIdx.y*128;
  mfma_core(A, NHID, Bt, NHID, NHID, row0, col0, lds, acc);
  EPI_LOOP(
    int rg = row_off + row;
    const float* g2 = ada + (size_t)(rg >> 12)*NADA + 5*NF;
    outp[(size_t)rg*NF + col] += g2[col]*(aval + b2[col]); )
}

// ---------------- small kernels ----------------
__global__ __launch_bounds__(256) void k_silu(const float* __restrict__ cond, float* __restrict__ sc) {
  int id = blockIdx.x*256 + threadIdx.x;
  if (id < NB*NF) { float c = cond[id]; sc[id] = c / (1.f + expf(-c)); }
}

__global__ __launch_bounds__(256) void k_ada(const float* __restrict__ sc, const float* __restrict__ adaW,
                                             const float* __restrict__ adab, float* __restrict__ ada) {
  int j = blockIdx.x*256 + threadIdx.x;
  int b = blockIdx.y;
  float acc = adab[j];
  const float* s = sc + b*NF;
  for (int k = 0; k < NF; ++k) acc += s[k] * adaW[(size_t)k*NADA + j];
  ada[(size_t)b*NADA + j] = acc;
}

__global__ __launch_bounds__(64) void k_param(
    const float* __restrict__ lAf, const float* __restrict__ Aif, const float* __restrict__ ldtf,
    const float* __restrict__ lAb, const float* __restrict__ Aib, const float* __restrict__ ldtb,
    float* __restrict__ Abar, float* __restrict__ coef, float* __restrict__ AbarL, float* __restrict__ Apow)
{
  int d = blockIdx.x, n = threadIdx.x;
  const float* lA  = d ? lAb  : lAf;
  const float* Ai  = d ? Aib  : Aif;
  const float* ldt = d ? ldtb : ldtf;
  float dt  = expf(ldt[n]);
  float Are = -expf(lA[n]);
  float Aim = Ai[n];
  float ar = Are*dt, ai = Aim*dt;
  float m = expf(ar);
  float Abr = m*cosf(ai), Abi = m*sinf(ai);
  int t = d*NST + n;
  Abar[2*t] = Abr; Abar[2*t+1] = Abi;
  float cr = Abr - 1.f, ci = Abi;
  float dr = Are + 1e-8f, di = Aim;
  float den = dr*dr + di*di;
  coef[2*t]   = (cr*dr + ci*di)/den;
  coef[2*t+1] = (ci*dr - cr*di)/den;
  for (int j = 0; j < LCH; ++j) {
    float p = (float)(j+1);
    float mp = expf(ar*p);
    Apow[(size_t)(t*LCH + j)*2 + 0] = mp*cosf(ai*p);
    Apow[(size_t)(t*LCH + j)*2 + 1] = mp*sinf(ai*p);
  }
  float mL = expf(ar*64.f);
  AbarL[2*t] = mL*cosf(ai*64.f); AbarL[2*t+1] = mL*sinf(ai*64.f);
}

// Bmat transposed bf16: Bmat_t[2c+p][f]
__global__ __launch_bounds__(256) void k_bmat_t(
    const float* __restrict__ Brf, const float* __restrict__ Bif,
    const float* __restrict__ Brb, const float* __restrict__ Bib,
    const float* __restrict__ coef, unsigned short* __restrict__ Bmat_t)
{
  int id = blockIdx.x*256 + threadIdx.x;     // over 128*1024
  int f = id & (NF-1), c = id >> 10;
  int d = c >> 6, n = c & 63;
  const float* Br = d ? Brb : Brf;
  const float* Bi = d ? Bib : Bif;
  float br = Br[(size_t)n*NF + f], bi = Bi[(size_t)n*NF + f];
  float crr = coef[2*c], cii = coef[2*c+1];
  Bmat_t[(size_t)(2*c)*NF + f]   = f2bf(crr*br - cii*bi);
  Bmat_t[(size_t)(2*c+1)*NF + f] = f2bf(crr*bi + cii*br);
}

// LayerNorm + AdaLN modulate, bf16 output into Acat region (ld = LDA)
__global__ __launch_bounds__(256) void k_ln_mod_bf(const float* __restrict__ xin, const float* __restrict__ ada,
                                                   int sh_off, int sc_off, unsigned short* __restrict__ outp) {
  const int row = blockIdx.x;
  const int b = row >> 12;
  const int tid = threadIdx.x;
  float4 v = ((const float4*)(xin + (size_t)row*NF))[tid];
  float s1 = v.x+v.y+v.z+v.w;
  float s2 = v.x*v.x + v.y*v.y + v.z*v.z + v.w*v.w;
  for (int off = 32; off > 0; off >>= 1) { s1 += __shfl_down(s1, off); s2 += __shfl_down(s2, off); }
  __shared__ float r1[4], r2[4];
  if ((tid & 63) == 0) { r1[tid>>6] = s1; r2[tid>>6] = s2; }
  __syncthreads();
  float S1 = r1[0]+r1[1]+r1[2]+r1[3];
  float S2 = r2[0]+r2[1]+r2[2]+r2[3];
  float mean = S1 * (1.0f/NF);
  float var  = S2 * (1.0f/NF) - mean*mean;
  float inv  = rsqrtf(var + 1e-5f);
  const float* arow = ada + (size_t)b*NADA;
  int f = tid << 2;
  ushort4 r;
  r.x = f2bf((v.x - mean)*inv*(1.f + arow[sc_off + f+0]) + arow[sh_off + f+0]);
  r.y = f2bf((v.y - mean)*inv*(1.f + arow[sc_off + f+1]) + arow[sh_off + f+1]);
  r.z = f2bf((v.z - mean)*inv*(1.f + arow[sc_off + f+2]) + arow[sh_off + f+2]);
  r.w = f2bf((v.w - mean)*inv*(1.f + arow[sc_off + f+3]) + arow[sh_off + f+3]);
  *(ushort4*)(outp + (size_t)row*LDA + f) = r;
}

// scan phase A: per-(b,chunk) local complex scan on fp32 bu
__global__ __launch_bounds__(128) void k_scanA(float* __restrict__ Bu, const float* __restrict__ Abar,
                                               float* __restrict__ P) {
  int t = threadIdx.x;
  int bc = blockIdx.x;
  int b = bc >> 6, c = bc & 63;
  int d = t >> 6;
  float2 A = ((const float2*)Abar)[t];
  float sr = 0.f, si = 0.f;
  size_t base = ((size_t)b*NSEQ)*(2*NCH);
  for (int j = 0; j < LCH; ++j) {
    int s = d ? (c*LCH + (LCH-1) - j) : (c*LCH + j);
    float2* p = (float2*)(Bu + base + (size_t)s*(2*NCH)) + t;
    float2 u = *p;
    float nr = A.x*sr - A.y*si + u.x;
    float ni = A.x*si + A.y*sr + u.y;
    sr = nr; si = ni;
    *p = make_float2(sr, si);
  }
  ((float2*)P)[(size_t)bc*NCH + t] = make_float2(sr, si);
}

__global__ __launch_bounds__(512) void k_scanB(const float* __restrict__ P, const float* __restrict__ AbarL,
                                               float* __restrict__ carry) {
  int t = threadIdx.x & (NCH-1);
  int b = threadIdx.x >> 7;
  int d = t >> 6;
  float2 AL = ((const float2*)AbarL)[t];
  float sr = 0.f, si = 0.f;
  if (d == 0) {
    for (int c = 0; c < NCHUNK; ++c) {
      ((float2*)carry)[((size_t)b*NCHUNK + c)*NCH + t] = make_float2(sr, si);
      float2 p = ((const float2*)P)[((size_t)b*NCHUNK + c)*NCH + t];
      float nr = AL.x*sr - AL.y*si + p.x;
      float ni = AL.x*si + AL.y*sr + p.y;
      sr = nr; si = ni;
    }
  } else {
    for (int c = NCHUNK-1; c >= 0; --c) {
      ((float2*)carry)[((size_t)b*NCHUNK + c)*NCH + t] = make_float2(sr, si);
      float2 p = ((const float2*)P)[((size_t)b*NCHUNK + c)*NCH + t];
      float nr = AL.x*sr - AL.y*si + p.x;
      float ni = AL.x*si + AL.y*sr + p.y;
      sr = nr; si = ni;
    }
  }
}

__global__ __launch_bounds__(128) void k_scanC(float* __restrict__ Bu, const float* __restrict__ Apow,
                                               const float* __restrict__ carry) {
  int t = threadIdx.x;
  int bc = blockIdx.x;
  int b = bc >> 6, c = bc & 63;
  int d = t >> 6;
  float2 E = ((const float2*)carry)[(size_t)bc*NCH + t];
  const float2* Ap = ((const float2*)Apow) + (size_t)t*LCH;
  size_t base = ((size_t)b*NSEQ)*(2*NCH);
  for (int j = 0; j < LCH; ++j) {
    int s = c*LCH + j;
    int tau = d ? (LCH-1 - j) : j;
    float2 ap = Ap[tau];
    float2* p = (float2*)(Bu + base + (size_t)s*(2*NCH)) + t;
    float2 v = *p;
    v.x += ap.x*E.x - ap.y*E.y;
    v.y += ap.x*E.y + ap.y*E.x;
    *p = v;
  }
}

// xs fp32 -> bf16 into Acat cols 0..255
__global__ __launch_bounds__(256) void k_xs_cvt(const float* __restrict__ bu, unsigned short* __restrict__ Acat) {
  int id = blockIdx.x*256 + threadIdx.x;     // over 16384*64
  int row = id >> 6, c4 = (id & 63) << 2;
  float4 v = *(const float4*)(bu + (size_t)row*(2*NCH) + c4);
  ushort4 r; r.x = f2bf(v.x); r.y = f2bf(v.y); r.z = f2bf(v.z); r.w = f2bf(v.w);
  *(ushort4*)(Acat + (size_t)row*LDA + c4) = r;
}

// G[r][fo] fp32 (folded C-projection into out_W)
__global__ __launch_bounds__(256) void k_g(
    const float* __restrict__ Crf, const float* __restrict__ Cif,
    const float* __restrict__ Crb, const float* __restrict__ Cib,
    const float* __restrict__ W, float* __restrict__ G)
{
  int g = blockIdx.x;
  int tid = threadIdx.x;
  int d = g >> 4;
  const float* Cr = d ? Crb : Crf;
  const float* Ci = d ? Cib : Cif;
  const float* Wd = W + (size_t)d*NF*NF;
  float4 acc[8];
#pragma unroll
  for (int rr = 0; rr < 8; ++rr) acc[rr] = make_float4(0.f,0.f,0.f,0.f);
  int c4 = tid << 2;
  for (int k = 0; k < NF; ++k) {
    float4 w = *(const float4*)(Wd + (size_t)k*NF + c4);
#pragma unroll
    for (int rr = 0; rr < 8; ++rr) {
      int n = (g*4 + (rr>>1)) & 63;
      float s = (rr & 1) ? Ci[(size_t)k*NST + n] : Cr[(size_t)k*NST + n];
      acc[rr].x += s*w.x; acc[rr].y += s*w.y; acc[rr].z += s*w.z; acc[rr].w += s*w.w;
    }
  }
#pragma unroll
  for (int rr = 0; rr < 8; ++rr) {
    int r = g*8 + rr;
    float sgn = (rr & 1) ? -1.f : 1.f;
    *(float4*)(G + (size_t)r*NF + c4) =
        make_float4(sgn*acc[rr].x, sgn*acc[rr].y, sgn*acc[rr].z, sgn*acc[rr].w);
  }
}

__global__ __launch_bounds__(256) void k_wd(const float* __restrict__ Df, const float* __restrict__ Db,
                                            const float* __restrict__ W, float* __restrict__ WD) {
  int id = blockIdx.x*256 + threadIdx.x;
  int fo = id & (NF-1); int f = id >> 10;
  WD[id] = Df[f]*W[(size_t)f*NF + fo] + Db[f]*W[(size_t)(NF+f)*NF + fo];
}

// tiled transpose + f32->bf16: src[R][C] -> dst[C][R] (dst leading dim ldd)
__global__ void k_tcvt(const float* __restrict__ src, int R, int C,
                       unsigned short* __restrict__ dst, int ldd) {
  __shared__ float t[32][33];
  int c0 = blockIdx.x*32, r0 = blockIdx.y*32;
  for (int rr = threadIdx.y; rr < 32; rr += 8)
    t[rr][threadIdx.x] = src[(size_t)(r0+rr)*C + c0 + threadIdx.x];
  __syncthreads();
  for (int rr = threadIdx.y; rr < 32; rr += 8)
    dst[(size_t)(c0+rr)*ldd + r0 + threadIdx.x] = f2bf(t[threadIdx.x][rr]);
}

// ---------------- launcher ----------------
extern "C" void kernel_launch(void* const* d_in, const int* in_sizes, int n_in,
                              void* d_out, int out_size, void* d_ws, size_t ws_size,
                              hipStream_t stream) {
  const bool sig = (in_sizes[4] == 64);
  const float* x    = (const float*)d_in[0];
  const float* cond = (const float*)d_in[1];
  const float* adaW = (const float*)d_in[2];
  const float* adab = (const float*)d_in[3];
  const int fwd0 = sig ? 4 : 11;
  const int bwd0 = sig ? 12 : 19;
  const float* outW = (const float*)d_in[sig ? 20 : 4];
  const float* outb = (const float*)d_in[sig ? 21 : 5];
  const float* W1   = (const float*)d_in[sig ? 22 : 6];
  const float* b1   = (const float*)d_in[sig ? 23 : 7];
  const float* W2   = (const float*)d_in[sig ? 24 : 8];
  const float* b2   = (const float*)d_in[sig ? 25 : 9];
  const float* lAf  = (const float*)d_in[fwd0+0];
  const float* Aif  = (const float*)d_in[fwd0+1];
  const float* Brf  = (const float*)d_in[fwd0+2];
  const float* Bif  = (const float*)d_in[fwd0+3];
  const float* Crf  = (const float*)d_in[fwd0+4];
  const float* Cif  = (const float*)d_in[fwd0+5];
  const float* Df   = (const float*)d_in[fwd0+6];
  const float* ldtf = (const float*)d_in[fwd0+7];
  const float* lAb  = (const float*)d_in[bwd0+0];
  const float* Aib  = (const float*)d_in[bwd0+1];
  const float* Brb  = (const float*)d_in[bwd0+2];
  const float* Bib  = (const float*)d_in[bwd0+3];
  const float* Crb  = (const float*)d_in[bwd0+4];
  const float* Cib  = (const float*)d_in[bwd0+5];
  const float* Db   = (const float*)d_in[bwd0+6];
  const float* ldtb = (const float*)d_in[bwd0+7];
  float* out = (float*)d_out;
  (void)n_in; (void)out_size; (void)ws_size;

  char* w = (char*)d_ws;
  auto alloc = [&](size_t bytes) { char* p = w; w += (bytes + 255) & ~(size_t)255; return p; };
  unsigned short* Acat   = (unsigned short*)alloc((size_t)NROWS*LDA*2);     // 41.9 MB
  unsigned short* mid    = (unsigned short*)alloc((size_t)MLP_ROWS*NHID*2); // 33.6 MB
  unsigned short* W1t    = (unsigned short*)alloc((size_t)NHID*NF*2);       // 8.4 MB
  unsigned short* W2t    = (unsigned short*)alloc((size_t)NF*NHID*2);       // 8.4 MB
  unsigned short* Bmat_t = (unsigned short*)alloc((size_t)2*NCH*NF*2);      // 0.5 MB
  unsigned short* Bcat   = (unsigned short*)alloc((size_t)NF*LDA*2);        // 2.6 MB
  float* bu    = (float*)alloc((size_t)NROWS*2*NCH*4);                      // 16.8 MB
  float* G     = (float*)alloc((size_t)2*NCH*NF*4);                         // 1.0 MB
  float* WD    = (float*)alloc((size_t)NF*NF*4);                            // 4.2 MB
  float* ada   = (float*)alloc((size_t)NB*NADA*4);
  float* sc    = (float*)alloc((size_t)NB*NF*4);
  float* Abar  = (float*)alloc(2*NCH*4);
  float* AbarL = (float*)alloc(2*NCH*4);
  float* coef  = (float*)alloc(2*NCH*4);
  float* Apow  = (float*)alloc((size_t)NCH*LCH*2*4);
  float* P     = (float*)alloc((size_t)NB*NCHUNK*NCH*2*4);
  float* carry = (float*)alloc((size_t)NB*NCHUNK*NCH*2*4);

  // conditioning + parameter tables
  k_silu<<<(NB*NF+255)/256, 256, 0, stream>>>(cond, sc);
  k_ada<<<dim3(NADA/256, NB), 256, 0, stream>>>(sc, adaW, adab, ada);
  k_param<<<2, 64, 0, stream>>>(lAf, Aif, ldtf, lAb, Aib, ldtb, Abar, coef, AbarL, Apow);
  k_bmat_t<<<(2*NCH*NF)/(2*256), 256, 0, stream>>>(Brf, Bif, Brb, Bib, coef, Bmat_t);

  // weight converts (bf16, transposed)
  k_tcvt<<<dim3(NHID/32, NF/32), dim3(32,8), 0, stream>>>(W1, NF, NHID, W1t, NF);
  k_tcvt<<<dim3(NF/32, NHID/32), dim3(32,8), 0, stream>>>(W2, NHID, NF, W2t, NHID);

  // LN1 -> h (bf16) into Acat cols 256..1279
  k_ln_mod_bf<<<NROWS, 256, 0, stream>>>(x, ada, 0, NF, Acat + 256);

  // Bu GEMM (bf16 MFMA) -> fp32 bu
  k_mm_bu<<<dim3(NROWS/128, (2*NCH)/128), 256, 0, stream>>>(Acat + 256, Bmat_t, bu);

  // chunked parallel scan (fp32)
  k_scanA<<<NB*NCHUNK, NCH, 0, stream>>>(bu, Abar, P);
  k_scanB<<<1, 512, 0, stream>>>(P, AbarL, carry);
  k_scanC<<<NB*NCHUNK, NCH, 0, stream>>>(bu, Apow, carry);
  k_xs_cvt<<<(NROWS*64)/256, 256, 0, stream>>>(bu, Acat);

  // folded projection matrices -> Bcat (bf16, [N=1024][K=1280])
  k_g<<<32, 256, 0, stream>>>(Crf, Cif, Crb, Cib, outW, G);
  k_tcvt<<<dim3(NF/32, (2*NCH)/32), dim3(32,8), 0, stream>>>(G, 2*NCH, NF, Bcat, LDA);
  k_wd<<<(NF*NF)/256, 256, 0, stream>>>(Df, Db, outW, WD);
  k_tcvt<<<dim3(NF/32, NF/32), dim3(32,8), 0, stream>>>(WD, NF, NF, Bcat + 256, LDA);

  // x1 = x + g1*(Acat @ Bcat^T + outb)
  k_mm_proj<<<dim3(NROWS/128, NF/128), 256, 0, stream>>>(Acat, Bcat, x, ada, outb, out);

  // LN2 -> h2 (bf16) into Acat cols 256..1279 (xs region dead now)
  k_ln_mod_bf<<<NROWS, 256, 0, stream>>>(out, ada, 3*NF, 4*NF, Acat + 256);

  // MLP in 4 row-chunks of 4096
  for (int ch = 0; ch < NMLP; ++ch) {
    const unsigned short* Ah2 = Acat + 256 + (size_t)ch*MLP_ROWS*LDA;
    k_mm_mlp1<<<dim3(MLP_ROWS/128, NHID/128), 256, 0, stream>>>(Ah2, W1t, b1, mid);
    k_mm_mlp2<<<dim3(MLP_ROWS/128, NF/128), 256, 0, stream>>>(mid, W2t, b2, ada, out, ch*MLP_ROWS);
  }
}

// Round 3
// 1007.955 us; speedup vs baseline: 5.9378x; 1.3437x over previous
//
#include <hip/hip_runtime.h>
#include <cstddef>

// ---------------- problem dims ----------------
#define NF    1024
#define NSEQ  4096
#define NB    4
#define NROWS (NB*NSEQ)      // 16384
#define NADA  6144
#define NHID  4096
#define NST   64
#define NCH   128            // dir(2) * state(64) complex channels
#define LCH   64             // scan chunk length
#define NCHUNK (NSEQ/LCH)    // 64
#define LDA   1280           // Acat leading dim (256 xs + 1024 h)

typedef __bf16 bf16x8 __attribute__((ext_vector_type(8)));
typedef float f32x4 __attribute__((ext_vector_type(4)));

__device__ __forceinline__ unsigned short f2bf(float x) {
  union { float f; unsigned int u; } v; v.f = x;
  unsigned int r = v.u + 0x7fffu + ((v.u >> 16) & 1u);
  return (unsigned short)(r >> 16);
}

__device__ __forceinline__ float gelu_tanh(float x) {
  float x3 = x*x*x;
  float u = 0.7978845608028654f*(x + 0.044715f*x3);
  return 0.5f*x*(1.f + tanhf(u));
}

// ============ MFMA GEMM core: 128x128 tile, BK=32 bf16, 256 thr (4 waves) ===
__device__ __forceinline__ void mfma_core(
    const unsigned short* __restrict__ A, int lda,
    const unsigned short* __restrict__ Bt, int ldb,
    int K, int row0, int col0, unsigned short* lds, f32x4 acc[4][4])
{
  const int tid  = threadIdx.x;
  const int wave = tid >> 6, lane = tid & 63;
  const int wm = wave & 1, wn = wave >> 1;
  const int sr = lane >> 2;
  const int sc = (lane & 3) << 3;
  const int fr = lane & 15, fq = lane >> 4;
  unsigned short* sA = lds;
  unsigned short* sB = lds + 128*32;
  const unsigned short* a0 = A + (size_t)row0*lda;
  const unsigned short* b0 = Bt + (size_t)col0*ldb;
  for (int k0 = 0; k0 < K; k0 += 32) {
#pragma unroll
    for (int s = 0; s < 2; ++s) {
      int i = wave*2 + s;
      int r = i*16 + sr;
      __builtin_amdgcn_global_load_lds(
          (const __attribute__((address_space(1))) void*)(a0 + (size_t)r*lda + k0 + sc),
          (__attribute__((address_space(3))) void*)(sA + i*512), 16, 0, 0);
      __builtin_amdgcn_global_load_lds(
          (const __attribute__((address_space(1))) void*)(b0 + (size_t)r*ldb + k0 + sc),
          (__attribute__((address_space(3))) void*)(sB + i*512), 16, 0, 0);
    }
    __syncthreads();
    bf16x8 af[4], bv[4];
#pragma unroll
    for (int t = 0; t < 4; ++t) {
      af[t] = *(const bf16x8*)(sA + (wm*64 + t*16 + fr)*32 + fq*8);
      bv[t] = *(const bf16x8*)(sB + (wn*64 + t*16 + fr)*32 + fq*8);
    }
#pragma unroll
    for (int i = 0; i < 4; ++i)
#pragma unroll
      for (int j = 0; j < 4; ++j)
        acc[i][j] = __builtin_amdgcn_mfma_f32_16x16x32_bf16(af[i], bv[j], acc[i][j], 0, 0, 0);
    __syncthreads();
  }
}

#define ACC_INIT f32x4 acc[4][4]; \
  _Pragma("unroll") for (int i = 0; i < 4; ++i) \
  _Pragma("unroll") for (int j = 0; j < 4; ++j) acc[i][j] = (f32x4){0.f,0.f,0.f,0.f};

// D mapping (m89-verified): col = n0 + (lane&15), row = m0 + (lane>>4)*4 + reg
#define EPI_LOOP(body) \
  { const int lane = threadIdx.x & 63, wave = threadIdx.x >> 6; \
    const int wm = wave & 1, wn = wave >> 1; \
    const int fr = lane & 15, fq = lane >> 4; \
    _Pragma("unroll") for (int i = 0; i < 4; ++i) \
    _Pragma("unroll") for (int j = 0; j < 4; ++j) \
    _Pragma("unroll") for (int r = 0; r < 4; ++r) { \
      int row = row0 + wm*64 + i*16 + fq*4 + r; \
      int col = col0 + wn*64 + j*16 + fr; \
      float aval = acc[i][j][r]; \
      body; } }

// Bu GEMM: h(bf16) @ Bmat_t^T -> bu fp32 [16384][256]
__global__ __launch_bounds__(256) void k_mm_bu(const unsigned short* __restrict__ A,
                                               const unsigned short* __restrict__ Bt,
                                               float* __restrict__ C) {
  __shared__ __align__(16) unsigned short lds[2*128*32];
  ACC_INIT
  int row0 = blockIdx.x*128, col0 = blockIdx.y*128;
  mfma_core(A, LDA, Bt, 1024, 1024, row0, col0, lds, acc);
  EPI_LOOP( C[(size_t)row*(2*NCH) + col] = aval; )
}

// G GEMM: Ccat[256][2048] @ Wot^T -> Bcat cols 0..255 (transposed store)
__global__ __launch_bounds__(256) void k_mm_g(const unsigned short* __restrict__ A,
                                              const unsigned short* __restrict__ Bt,
                                              unsigned short* __restrict__ Bcat) {
  __shared__ __align__(16) unsigned short lds[2*128*32];
  ACC_INIT
  int row0 = blockIdx.x*128, col0 = blockIdx.y*128;
  mfma_core(A, 2048, Bt, 2048, 2048, row0, col0, lds, acc);
  EPI_LOOP( Bcat[(size_t)col*LDA + row] = f2bf(aval); )
}

// proj: out = x + g1 * (Acat@Bcat^T + outb)
__global__ __launch_bounds__(256) void k_mm_proj(const unsigned short* __restrict__ A,
                                                 const unsigned short* __restrict__ Bt,
                                                 const float* __restrict__ x,
                                                 const float* __restrict__ ada,
                                                 const float* __restrict__ outb,
                                                 float* __restrict__ outp) {
  __shared__ __align__(16) unsigned short lds[2*128*32];
  ACC_INIT
  int row0 = blockIdx.x*128, col0 = blockIdx.y*128;
  mfma_core(A, LDA, Bt, LDA, LDA, row0, col0, lds, acc);
  EPI_LOOP(
    const float* g1 = ada + (size_t)(row >> 12)*NADA + 2*NF;
    outp[(size_t)row*NF + col] = x[(size_t)row*NF + col] + g1[col]*(aval + outb[col]); )
}

// mlp1: mid = bf16(gelu(h2@W1t^T + b1))
__global__ __launch_bounds__(256) void k_mm_mlp1(const unsigned short* __restrict__ A,
                                                 const unsigned short* __restrict__ Bt,
                                                 const float* __restrict__ b1,
                                                 unsigned short* __restrict__ mid) {
  __shared__ __align__(16) unsigned short lds[2*128*32];
  ACC_INIT
  int row0 = blockIdx.x*128, col0 = blockIdx.y*128;
  mfma_core(A, LDA, Bt, 1024, 1024, row0, col0, lds, acc);
  EPI_LOOP( mid[(size_t)row*NHID + col] = f2bf(gelu_tanh(aval + b1[col])); )
}

// mlp2: out += g2 * (mid@W2t^T + b2)
__global__ __launch_bounds__(256) void k_mm_mlp2(const unsigned short* __restrict__ A,
                                                 const unsigned short* __restrict__ Bt,
                                                 const float* __restrict__ b2,
                                                 const float* __restrict__ ada,
                                                 float* __restrict__ outp, int row_off) {
  __shared__ __align__(16) unsigned short lds[2*128*32];
  ACC_INIT
  int row0 = blockIdx.x*128, col0 = blockIdx.y*128;
  mfma_core(A, NHID, Bt, NHID, NHID, row0, col0, lds, acc);
  EPI_LOOP(
    int rg = row_off + row;
    const float* g2 = ada + (size_t)(rg >> 12)*NADA + 5*NF;
    outp[(size_t)rg*NF + col] += g2[col]*(aval + b2[col]); )
}

// ---------------- small kernels ----------------
__global__ __launch_bounds__(256) void k_silu(const float* __restrict__ cond, float* __restrict__ sc) {
  int id = blockIdx.x*256 + threadIdx.x;
  if (id < NB*NF) { float c = cond[id]; sc[id] = c / (1.f + expf(-c)); }
}

__global__ __launch_bounds__(256) void k_ada(const float* __restrict__ sc, const float* __restrict__ adaW,
                                             const float* __restrict__ adab, float* __restrict__ ada) {
  int j = blockIdx.x*256 + threadIdx.x;
  int b = blockIdx.y;
  float acc = adab[j];
  const float* s = sc + b*NF;
  for (int k = 0; k < NF; ++k) acc += s[k] * adaW[(size_t)k*NADA + j];
  ada[(size_t)b*NADA + j] = acc;
}

__global__ __launch_bounds__(64) void k_param(
    const float* __restrict__ lAf, const float* __restrict__ Aif, const float* __restrict__ ldtf,
    const float* __restrict__ lAb, const float* __restrict__ Aib, const float* __restrict__ ldtb,
    float* __restrict__ Abar, float* __restrict__ coef, float* __restrict__ AbarL, float* __restrict__ Apow)
{
  int d = blockIdx.x, n = threadIdx.x;
  const float* lA  = d ? lAb  : lAf;
  const float* Ai  = d ? Aib  : Aif;
  const float* ldt = d ? ldtb : ldtf;
  float dt  = expf(ldt[n]);
  float Are = -expf(lA[n]);
  float Aim = Ai[n];
  float ar = Are*dt, ai = Aim*dt;
  float m = expf(ar);
  float Abr = m*cosf(ai), Abi = m*sinf(ai);
  int t = d*NST + n;
  Abar[2*t] = Abr; Abar[2*t+1] = Abi;
  float cr = Abr - 1.f, ci = Abi;
  float dr = Are + 1e-8f, di = Aim;
  float den = dr*dr + di*di;
  coef[2*t]   = (cr*dr + ci*di)/den;
  coef[2*t+1] = (ci*dr - cr*di)/den;
  for (int j = 0; j < LCH; ++j) {
    float p = (float)(j+1);
    float mp = expf(ar*p);
    Apow[(size_t)(t*LCH + j)*2 + 0] = mp*cosf(ai*p);
    Apow[(size_t)(t*LCH + j)*2 + 1] = mp*sinf(ai*p);
  }
  float mL = expf(ar*64.f);
  AbarL[2*t] = mL*cosf(ai*64.f); AbarL[2*t+1] = mL*sinf(ai*64.f);
}

// Bmat transposed bf16: Bmat_t[2c+p][f]
__global__ __launch_bounds__(256) void k_bmat_t(
    const float* __restrict__ Brf, const float* __restrict__ Bif,
    const float* __restrict__ Brb, const float* __restrict__ Bib,
    const float* __restrict__ coef, unsigned short* __restrict__ Bmat_t)
{
  int id = blockIdx.x*256 + threadIdx.x;     // over 128*1024
  int f = id & (NF-1), c = id >> 10;
  int d = c >> 6, n = c & 63;
  const float* Br = d ? Brb : Brf;
  const float* Bi = d ? Bib : Bif;
  float br = Br[(size_t)n*NF + f], bi = Bi[(size_t)n*NF + f];
  float crr = coef[2*c], cii = coef[2*c+1];
  Bmat_t[(size_t)(2*c)*NF + f]   = f2bf(crr*br - cii*bi);
  Bmat_t[(size_t)(2*c+1)*NF + f] = f2bf(crr*bi + cii*br);
}

// Ccat bf16 [256 r][2048 f']: sign-folded C, zero outside own direction block
__global__ __launch_bounds__(256) void k_ccat(
    const float* __restrict__ Crf, const float* __restrict__ Cif,
    const float* __restrict__ Crb, const float* __restrict__ Cib,
    unsigned short* __restrict__ Ccat)
{
  int id = blockIdx.x*256 + threadIdx.x;     // over 256*2048
  int fp = id & 2047, r = id >> 11;
  int p = r & 1, c = r >> 1, d = c >> 6, n = c & 63;
  int fd = fp >> 10, f = fp & 1023;
  float v = 0.f;
  if (fd == d) {
    const float* Cr = d ? Crb : Crf;
    const float* Ci = d ? Cib : Cif;
    v = p ? -Ci[(size_t)f*NST + n] : Cr[(size_t)f*NST + n];
  }
  Ccat[id] = f2bf(v);
}

// LayerNorm + AdaLN modulate, bf16 output into Acat region (ld = LDA)
__global__ __launch_bounds__(256) void k_ln_mod_bf(const float* __restrict__ xin, const float* __restrict__ ada,
                                                   int sh_off, int sc_off, unsigned short* __restrict__ outp) {
  const int row = blockIdx.x;
  const int b = row >> 12;
  const int tid = threadIdx.x;
  float4 v = ((const float4*)(xin + (size_t)row*NF))[tid];
  float s1 = v.x+v.y+v.z+v.w;
  float s2 = v.x*v.x + v.y*v.y + v.z*v.z + v.w*v.w;
  for (int off = 32; off > 0; off >>= 1) { s1 += __shfl_down(s1, off); s2 += __shfl_down(s2, off); }
  __shared__ float r1[4], r2[4];
  if ((tid & 63) == 0) { r1[tid>>6] = s1; r2[tid>>6] = s2; }
  __syncthreads();
  float S1 = r1[0]+r1[1]+r1[2]+r1[3];
  float S2 = r2[0]+r2[1]+r2[2]+r2[3];
  float mean = S1 * (1.0f/NF);
  float var  = S2 * (1.0f/NF) - mean*mean;
  float inv  = rsqrtf(var + 1e-5f);
  const float* arow = ada + (size_t)b*NADA;
  int f = tid << 2;
  ushort4 r;
  r.x = f2bf((v.x - mean)*inv*(1.f + arow[sc_off + f+0]) + arow[sh_off + f+0]);
  r.y = f2bf((v.y - mean)*inv*(1.f + arow[sc_off + f+1]) + arow[sh_off + f+1]);
  r.z = f2bf((v.z - mean)*inv*(1.f + arow[sc_off + f+2]) + arow[sh_off + f+2]);
  r.w = f2bf((v.w - mean)*inv*(1.f + arow[sc_off + f+3]) + arow[sh_off + f+3]);
  *(ushort4*)(outp + (size_t)row*LDA + f) = r;
}

// scan phase A: per-(b,chunk) local complex scan on fp32 bu
__global__ __launch_bounds__(128) void k_scanA(float* __restrict__ Bu, const float* __restrict__ Abar,
                                               float* __restrict__ P) {
  int t = threadIdx.x;
  int bc = blockIdx.x;
  int b = bc >> 6, c = bc & 63;
  int d = t >> 6;
  float2 A = ((const float2*)Abar)[t];
  float sr = 0.f, si = 0.f;
  size_t base = ((size_t)b*NSEQ)*(2*NCH);
  for (int j = 0; j < LCH; ++j) {
    int s = d ? (c*LCH + (LCH-1) - j) : (c*LCH + j);
    float2* p = (float2*)(Bu + base + (size_t)s*(2*NCH)) + t;
    float2 u = *p;
    float nr = A.x*sr - A.y*si + u.x;
    float ni = A.x*si + A.y*sr + u.y;
    sr = nr; si = ni;
    *p = make_float2(sr, si);
  }
  ((float2*)P)[(size_t)bc*NCH + t] = make_float2(sr, si);
}

__global__ __launch_bounds__(512) void k_scanB(const float* __restrict__ P, const float* __restrict__ AbarL,
                                               float* __restrict__ carry) {
  int t = threadIdx.x & (NCH-1);
  int b = threadIdx.x >> 7;
  int d = t >> 6;
  float2 AL = ((const float2*)AbarL)[t];
  float sr = 0.f, si = 0.f;
  if (d == 0) {
    for (int c = 0; c < NCHUNK; ++c) {
      ((float2*)carry)[((size_t)b*NCHUNK + c)*NCH + t] = make_float2(sr, si);
      float2 p = ((const float2*)P)[((size_t)b*NCHUNK + c)*NCH + t];
      float nr = AL.x*sr - AL.y*si + p.x;
      float ni = AL.x*si + AL.y*sr + p.y;
      sr = nr; si = ni;
    }
  } else {
    for (int c = NCHUNK-1; c >= 0; --c) {
      ((float2*)carry)[((size_t)b*NCHUNK + c)*NCH + t] = make_float2(sr, si);
      float2 p = ((const float2*)P)[((size_t)b*NCHUNK + c)*NCH + t];
      float nr = AL.x*sr - AL.y*si + p.x;
      float ni = AL.x*si + AL.y*sr + p.y;
      sr = nr; si = ni;
    }
  }
}

// scan phase C fused with bf16 convert: Acat cols 0..255 <- local + A^(tau+1)*carry
__global__ __launch_bounds__(128) void k_scanC(const float* __restrict__ Bu, const float* __restrict__ Apow,
                                               const float* __restrict__ carry,
                                               unsigned short* __restrict__ Acat) {
  int t = threadIdx.x;
  int bc = blockIdx.x;
  int b = bc >> 6, c = bc & 63;
  int d = t >> 6;
  float2 E = ((const float2*)carry)[(size_t)bc*NCH + t];
  const float2* Ap = ((const float2*)Apow) + (size_t)t*LCH;
  size_t base = ((size_t)b*NSEQ)*(2*NCH);
  for (int j = 0; j < LCH; ++j) {
    int s = c*LCH + j;
    int tau = d ? (LCH-1 - j) : j;
    float2 ap = Ap[tau];
    float2 v = *((const float2*)(Bu + base + (size_t)s*(2*NCH)) + t);
    v.x += ap.x*E.x - ap.y*E.y;
    v.y += ap.x*E.y + ap.y*E.x;
    ushort2 o; o.x = f2bf(v.x); o.y = f2bf(v.y);
    *(ushort2*)(Acat + (size_t)(b*NSEQ + s)*LDA + 2*t) = o;
  }
}

// tiled transpose + f32->bf16: src[R][C] -> dst[C][R] (dst leading dim ldd)
__global__ void k_tcvt(const float* __restrict__ src, int R, int C,
                       unsigned short* __restrict__ dst, int ldd) {
  __shared__ float t[32][33];
  int c0 = blockIdx.x*32, r0 = blockIdx.y*32;
  for (int rr = threadIdx.y; rr < 32; rr += 8)
    t[rr][threadIdx.x] = src[(size_t)(r0+rr)*C + c0 + threadIdx.x];
  __syncthreads();
  for (int rr = threadIdx.y; rr < 32; rr += 8)
    dst[(size_t)(c0+rr)*ldd + r0 + threadIdx.x] = f2bf(t[threadIdx.x][rr]);
}

// fused WD transpose: dst[fo][f] = bf16(Df[f]*W[f][fo] + Db[f]*W[1024+f][fo]); dst ld = LDA
__global__ void k_wd_t(const float* __restrict__ Df, const float* __restrict__ Db,
                       const float* __restrict__ W, unsigned short* __restrict__ dst) {
  __shared__ float t1[32][33], t2[32][33];
  __shared__ float df[32], db[32];
  int fo0 = blockIdx.x*32, f0 = blockIdx.y*32;
  for (int rr = threadIdx.y; rr < 32; rr += 8) {
    t1[rr][threadIdx.x] = W[(size_t)(f0+rr)*NF + fo0 + threadIdx.x];
    t2[rr][threadIdx.x] = W[(size_t)(NF+f0+rr)*NF + fo0 + threadIdx.x];
  }
  if (threadIdx.y == 0) { df[threadIdx.x] = Df[f0+threadIdx.x]; db[threadIdx.x] = Db[f0+threadIdx.x]; }
  __syncthreads();
  for (int rr = threadIdx.y; rr < 32; rr += 8)
    dst[(size_t)(fo0+rr)*LDA + f0 + threadIdx.x] =
        f2bf(df[threadIdx.x]*t1[threadIdx.x][rr] + db[threadIdx.x]*t2[threadIdx.x][rr]);
}

// ---------------- launcher ----------------
extern "C" void kernel_launch(void* const* d_in, const int* in_sizes, int n_in,
                              void* d_out, int out_size, void* d_ws, size_t ws_size,
                              hipStream_t stream) {
  const bool sig = (in_sizes[4] == 64);
  const float* x    = (const float*)d_in[0];
  const float* cond = (const float*)d_in[1];
  const float* adaW = (const float*)d_in[2];
  const float* adab = (const float*)d_in[3];
  const int fwd0 = sig ? 4 : 11;
  const int bwd0 = sig ? 12 : 19;
  const float* outW = (const float*)d_in[sig ? 20 : 4];
  const float* outb = (const float*)d_in[sig ? 21 : 5];
  const float* W1   = (const float*)d_in[sig ? 22 : 6];
  const float* b1   = (const float*)d_in[sig ? 23 : 7];
  const float* W2   = (const float*)d_in[sig ? 24 : 8];
  const float* b2   = (const float*)d_in[sig ? 25 : 9];
  const float* lAf  = (const float*)d_in[fwd0+0];
  const float* Aif  = (const float*)d_in[fwd0+1];
  const float* Brf  = (const float*)d_in[fwd0+2];
  const float* Bif  = (const float*)d_in[fwd0+3];
  const float* Crf  = (const float*)d_in[fwd0+4];
  const float* Cif  = (const float*)d_in[fwd0+5];
  const float* Df   = (const float*)d_in[fwd0+6];
  const float* ldtf = (const float*)d_in[fwd0+7];
  const float* lAb  = (const float*)d_in[bwd0+0];
  const float* Aib  = (const float*)d_in[bwd0+1];
  const float* Brb  = (const float*)d_in[bwd0+2];
  const float* Bib  = (const float*)d_in[bwd0+3];
  const float* Crb  = (const float*)d_in[bwd0+4];
  const float* Cib  = (const float*)d_in[bwd0+5];
  const float* Db   = (const float*)d_in[bwd0+6];
  const float* ldtb = (const float*)d_in[bwd0+7];
  float* out = (float*)d_out;
  (void)n_in; (void)out_size;

  char* w = (char*)d_ws;
  auto alloc = [&](size_t bytes) { char* p = w; w += (bytes + 255) & ~(size_t)255; return p; };
  unsigned short* Acat   = (unsigned short*)alloc((size_t)NROWS*LDA*2);     // 41.9 MB
  unsigned short* W1t    = (unsigned short*)alloc((size_t)NHID*NF*2);       // 8.4 MB
  unsigned short* W2t    = (unsigned short*)alloc((size_t)NF*NHID*2);       // 8.4 MB
  unsigned short* Wot    = (unsigned short*)alloc((size_t)NF*2048*2);       // 4.2 MB
  unsigned short* Ccat   = (unsigned short*)alloc((size_t)256*2048*2);      // 1.0 MB
  unsigned short* Bmat_t = (unsigned short*)alloc((size_t)2*NCH*NF*2);      // 0.5 MB
  unsigned short* Bcat   = (unsigned short*)alloc((size_t)NF*LDA*2);        // 2.6 MB
  float* bu    = (float*)alloc((size_t)NROWS*2*NCH*4);                      // 16.8 MB
  float* ada   = (float*)alloc((size_t)NB*NADA*4);
  float* sc    = (float*)alloc((size_t)NB*NF*4);
  float* Abar  = (float*)alloc(2*NCH*4);
  float* AbarL = (float*)alloc(2*NCH*4);
  float* coef  = (float*)alloc(2*NCH*4);
  float* Apow  = (float*)alloc((size_t)NCH*LCH*2*4);
  float* P     = (float*)alloc((size_t)NB*NCHUNK*NCH*2*4);
  float* carry = (float*)alloc((size_t)NB*NCHUNK*NCH*2*4);
  // mid: as big as workspace allows (16384 / 8192 / 4096 rows)
  size_t used = (size_t)(w - (char*)d_ws);
  int mrows = NROWS;
  while (mrows > 4096 && used + (size_t)mrows*NHID*2 > ws_size) mrows >>= 1;
  unsigned short* mid = (unsigned short*)alloc((size_t)mrows*NHID*2);

  // conditioning + parameter tables
  k_silu<<<(NB*NF+255)/256, 256, 0, stream>>>(cond, sc);
  k_ada<<<dim3(NADA/256, NB), 256, 0, stream>>>(sc, adaW, adab, ada);
  k_param<<<2, 64, 0, stream>>>(lAf, Aif, ldtf, lAb, Aib, ldtb, Abar, coef, AbarL, Apow);
  k_bmat_t<<<(2*NCH*NF)/(2*256), 256, 0, stream>>>(Brf, Bif, Brb, Bib, coef, Bmat_t);
  k_ccat<<<(256*2048)/256, 256, 0, stream>>>(Crf, Cif, Crb, Cib, Ccat);

  // weight converts (bf16, transposed)
  k_tcvt<<<dim3(NHID/32, NF/32), dim3(32,8), 0, stream>>>(W1, NF, NHID, W1t, NF);
  k_tcvt<<<dim3(NF/32, NHID/32), dim3(32,8), 0, stream>>>(W2, NHID, NF, W2t, NHID);
  k_tcvt<<<dim3(NF/32, 2048/32), dim3(32,8), 0, stream>>>(outW, 2048, NF, Wot, 2048);

  // Bcat: G part (MFMA) + WD part (fused transpose)
  k_mm_g<<<dim3(2, NF/128), 256, 0, stream>>>(Ccat, Wot, Bcat);
  k_wd_t<<<dim3(NF/32, NF/32), dim3(32,8), 0, stream>>>(Df, Db, outW, Bcat + 256);

  // LN1 -> h (bf16) into Acat cols 256..1279
  k_ln_mod_bf<<<NROWS, 256, 0, stream>>>(x, ada, 0, NF, Acat + 256);

  // Bu GEMM (bf16 MFMA) -> fp32 bu
  k_mm_bu<<<dim3(NROWS/128, (2*NCH)/128), 256, 0, stream>>>(Acat + 256, Bmat_t, bu);

  // chunked parallel scan (fp32), phase C writes bf16 xs into Acat cols 0..255
  k_scanA<<<NB*NCHUNK, NCH, 0, stream>>>(bu, Abar, P);
  k_scanB<<<1, 512, 0, stream>>>(P, AbarL, carry);
  k_scanC<<<NB*NCHUNK, NCH, 0, stream>>>(bu, Apow, carry, Acat);

  // x1 = x + g1*(Acat @ Bcat^T + outb)
  k_mm_proj<<<dim3(NROWS/128, NF/128), 256, 0, stream>>>(Acat, Bcat, x, ada, outb, out);

  // LN2 -> h2 (bf16) into Acat cols 256..1279 (xs region dead now)
  k_ln_mod_bf<<<NROWS, 256, 0, stream>>>(out, ada, 3*NF, 4*NF, Acat + 256);

  // MLP (row-chunked only if workspace demands it)
  for (int r0 = 0; r0 < NROWS; r0 += mrows) {
    k_mm_mlp1<<<dim3(mrows/128, NHID/128), 256, 0, stream>>>(Acat + 256 + (size_t)r0*LDA, W1t, b1, mid);
    k_mm_mlp2<<<dim3(mrows/128, NF/128), 256, 0, stream>>>(mid, W2t, b2, ada, out, r0);
  }
}

// Round 4
// 791.368 us; speedup vs baseline: 7.5629x; 1.2737x over previous
//
#include <hip/hip_runtime.h>
#include <cstddef>

// ---------------- problem dims ----------------
#define NF    1024
#define NSEQ  4096
#define NB    4
#define NROWS (NB*NSEQ)      // 16384
#define NADA  6144
#define NHID  4096
#define NST   64
#define NCH   128            // dir(2) * state(64) complex channels
#define LCH   64             // scan chunk length
#define NCHUNK (NSEQ/LCH)    // 64
#define LDA   1280           // Acat leading dim (256 xs + 1024 h)

typedef __bf16 bf16x8 __attribute__((ext_vector_type(8)));
typedef float f32x4 __attribute__((ext_vector_type(4)));

__device__ __forceinline__ unsigned short f2bf(float x) {
  union { float f; unsigned int u; } v; v.f = x;
  unsigned int r = v.u + 0x7fffu + ((v.u >> 16) & 1u);
  return (unsigned short)(r >> 16);
}

__device__ __forceinline__ float gelu_tanh(float x) {
  float x3 = x*x*x;
  float u = 0.7978845608028654f*(x + 0.044715f*x3);
  return 0.5f*x*(1.f + tanhf(u));
}

// ============ templated MFMA GEMM core =====================================
// Block tile TM x TN, wave grid WM x WN (WM*WN = 4 waves, 256 thr).
// A row-major [M][lda], Bt row-major [N][ldb]. BK=32 bf16.
// global_load_lds width=16 staging, ds_read_b128 frags, 16x16x32 MFMA.
template<int TM, int TN, int WM, int WN>
__device__ __forceinline__ void mfma_core(
    const unsigned short* __restrict__ A, int lda,
    const unsigned short* __restrict__ Bt, int ldb,
    int K, int row0, int col0, unsigned short* lds, f32x4* acc)
{
  constexpr int MI = TM/(16*WM), NJ = TN/(16*WN);
  const int tid  = threadIdx.x;
  const int wave = tid >> 6, lane = tid & 63;
  const int wm = wave % WM, wn = wave / WM;
  const int sr = lane >> 2;
  const int sc = (lane & 3) << 3;
  const int fr = lane & 15, fq = lane >> 4;
  unsigned short* sA = lds;            // [TM][32]
  unsigned short* sB = lds + TM*32;    // [TN][32]
  const unsigned short* a0 = A + (size_t)row0*lda;
  const unsigned short* b0 = Bt + (size_t)col0*ldb;
  for (int k0 = 0; k0 < K; k0 += 32) {
#pragma unroll
    for (int s = 0; s < TM/64; ++s) {
      int u = s*4 + wave;
      int r = u*16 + sr;
      __builtin_amdgcn_global_load_lds(
          (const __attribute__((address_space(1))) void*)(a0 + (size_t)r*lda + k0 + sc),
          (__attribute__((address_space(3))) void*)(sA + u*512), 16, 0, 0);
    }
#pragma unroll
    for (int s = 0; s < TN/64; ++s) {
      int u = s*4 + wave;
      int r = u*16 + sr;
      __builtin_amdgcn_global_load_lds(
          (const __attribute__((address_space(1))) void*)(b0 + (size_t)r*ldb + k0 + sc),
          (__attribute__((address_space(3))) void*)(sB + u*512), 16, 0, 0);
    }
    __syncthreads();
    bf16x8 af[MI], bv[NJ];
#pragma unroll
    for (int i = 0; i < MI; ++i)
      af[i] = *(const bf16x8*)(sA + (wm*(MI*16) + i*16 + fr)*32 + fq*8);
#pragma unroll
    for (int j = 0; j < NJ; ++j)
      bv[j] = *(const bf16x8*)(sB + (wn*(NJ*16) + j*16 + fr)*32 + fq*8);
#pragma unroll
    for (int i = 0; i < MI; ++i)
#pragma unroll
      for (int j = 0; j < NJ; ++j)
        acc[i*NJ+j] = __builtin_amdgcn_mfma_f32_16x16x32_bf16(af[i], bv[j], acc[i*NJ+j], 0, 0, 0);
    __syncthreads();
  }
}

#define ACC_INIT(N_) f32x4 acc[N_]; \
  _Pragma("unroll") for (int z_ = 0; z_ < N_; ++z_) acc[z_] = (f32x4){0.f,0.f,0.f,0.f};

// D mapping (m89-verified): col = n0 + (lane&15), row = m0 + (lane>>4)*4 + reg
#define EPI_LOOP(WM_, MI_, NJ_, body) \
  { const int lane = threadIdx.x & 63, wave = threadIdx.x >> 6; \
    const int wm = wave % WM_, wn = wave / WM_; \
    const int fr = lane & 15, fq = lane >> 4; \
    _Pragma("unroll") for (int i = 0; i < MI_; ++i) \
    _Pragma("unroll") for (int j = 0; j < NJ_; ++j) \
    _Pragma("unroll") for (int r = 0; r < 4; ++r) { \
      int row = row0 + wm*(MI_*16) + i*16 + fq*4 + r; \
      int col = col0 + wn*(NJ_*16) + j*16 + fr; \
      float aval = acc[i*NJ_+j][r]; \
      body; } }

// Bu GEMM: h(bf16) @ Bmat_t^T -> bu fp32 [16384][256]; 64x128 tile, grid (256,2)
__global__ __launch_bounds__(256, 4) void k_mm_bu(const unsigned short* __restrict__ A,
                                                  const unsigned short* __restrict__ Bt,
                                                  float* __restrict__ C) {
  __shared__ __align__(16) unsigned short lds[(64+128)*32];
  ACC_INIT(8)
  int row0 = blockIdx.x*64, col0 = blockIdx.y*128;
  mfma_core<64,128,1,4>(A, LDA, Bt, 1024, 1024, row0, col0, lds, acc);
  EPI_LOOP(1, 4, 2, C[(size_t)row*(2*NCH) + col] = aval; )
}

// G GEMM: Ccat[256][2048] @ Wot^T -> Bcat cols 0..255 (transposed store); grid (4,8)
__global__ __launch_bounds__(256, 4) void k_mm_g(const unsigned short* __restrict__ A,
                                                 const unsigned short* __restrict__ Bt,
                                                 unsigned short* __restrict__ Bcat) {
  __shared__ __align__(16) unsigned short lds[(64+128)*32];
  ACC_INIT(8)
  int row0 = blockIdx.x*64, col0 = blockIdx.y*128;
  mfma_core<64,128,1,4>(A, 2048, Bt, 2048, 2048, row0, col0, lds, acc);
  EPI_LOOP(1, 4, 2, Bcat[(size_t)col*LDA + row] = f2bf(aval); )
}

// proj: out = x + g1 * (Acat@Bcat^T + outb); 128x128 tile
__global__ __launch_bounds__(256, 3) void k_mm_proj(const unsigned short* __restrict__ A,
                                                    const unsigned short* __restrict__ Bt,
                                                    const float* __restrict__ x,
                                                    const float* __restrict__ ada,
                                                    const float* __restrict__ outb,
                                                    float* __restrict__ outp) {
  __shared__ __align__(16) unsigned short lds[2*128*32];
  ACC_INIT(16)
  int row0 = blockIdx.x*128, col0 = blockIdx.y*128;
  mfma_core<128,128,2,2>(A, LDA, Bt, LDA, LDA, row0, col0, lds, acc);
  EPI_LOOP(2, 4, 4,
    const float* g1 = ada + (size_t)(row >> 12)*NADA + 2*NF;
    outp[(size_t)row*NF + col] = x[(size_t)row*NF + col] + g1[col]*(aval + outb[col]); )
}

// mlp1: mid = bf16(gelu(h2@W1t^T + b1)); 128x128 tile
__global__ __launch_bounds__(256, 3) void k_mm_mlp1(const unsigned short* __restrict__ A,
                                                    const unsigned short* __restrict__ Bt,
                                                    const float* __restrict__ b1,
                                                    unsigned short* __restrict__ mid) {
  __shared__ __align__(16) unsigned short lds[2*128*32];
  ACC_INIT(16)
  int row0 = blockIdx.x*128, col0 = blockIdx.y*128;
  mfma_core<128,128,2,2>(A, LDA, Bt, 1024, 1024, row0, col0, lds, acc);
  EPI_LOOP(2, 4, 4, mid[(size_t)row*NHID + col] = f2bf(gelu_tanh(aval + b1[col])); )
}

// mlp2: out += g2 * (mid@W2t^T + b2); 128x128 tile
__global__ __launch_bounds__(256, 3) void k_mm_mlp2(const unsigned short* __restrict__ A,
                                                    const unsigned short* __restrict__ Bt,
                                                    const float* __restrict__ b2,
                                                    const float* __restrict__ ada,
                                                    float* __restrict__ outp, int row_off) {
  __shared__ __align__(16) unsigned short lds[2*128*32];
  ACC_INIT(16)
  int row0 = blockIdx.x*128, col0 = blockIdx.y*128;
  mfma_core<128,128,2,2>(A, NHID, Bt, NHID, NHID, row0, col0, lds, acc);
  EPI_LOOP(2, 4, 4,
    int rg = row_off + row;
    const float* g2 = ada + (size_t)(rg >> 12)*NADA + 5*NF;
    outp[(size_t)rg*NF + col] += g2[col]*(aval + b2[col]); )
}

// ---------------- small kernels ----------------
__global__ __launch_bounds__(256) void k_silu(const float* __restrict__ cond, float* __restrict__ sc) {
  int id = blockIdx.x*256 + threadIdx.x;
  if (id < NB*NF) { float c = cond[id]; sc[id] = c / (1.f + expf(-c)); }
}

// ada phase 1: k-split partials. grid (NADA/256, NB, 8)
__global__ __launch_bounds__(256) void k_ada1(const float* __restrict__ sc, const float* __restrict__ adaW,
                                              float* __restrict__ part) {
  int j = blockIdx.x*256 + threadIdx.x;
  int b = blockIdx.y, z = blockIdx.z;
  float acc = 0.f;
  const float* s = sc + b*NF;
  int k0 = z*128;
  for (int k = k0; k < k0+128; ++k) acc += s[k] * adaW[(size_t)k*NADA + j];
  part[((size_t)(z*NB + b))*NADA + j] = acc;
}

// ada phase 2: reduce 8 partials + bias. grid (NADA/256, NB)
__global__ __launch_bounds__(256) void k_ada2(const float* __restrict__ part, const float* __restrict__ adab,
                                              float* __restrict__ ada) {
  int j = blockIdx.x*256 + threadIdx.x;
  int b = blockIdx.y;
  float acc = adab[j];
#pragma unroll
  for (int z = 0; z < 8; ++z) acc += part[((size_t)(z*NB + b))*NADA + j];
  ada[(size_t)b*NADA + j] = acc;
}

__global__ __launch_bounds__(64) void k_param(
    const float* __restrict__ lAf, const float* __restrict__ Aif, const float* __restrict__ ldtf,
    const float* __restrict__ lAb, const float* __restrict__ Aib, const float* __restrict__ ldtb,
    float* __restrict__ Abar, float* __restrict__ coef, float* __restrict__ AbarL, float* __restrict__ Apow)
{
  int d = blockIdx.x, n = threadIdx.x;
  const float* lA  = d ? lAb  : lAf;
  const float* Ai  = d ? Aib  : Aif;
  const float* ldt = d ? ldtb : ldtf;
  float dt  = expf(ldt[n]);
  float Are = -expf(lA[n]);
  float Aim = Ai[n];
  float ar = Are*dt, ai = Aim*dt;
  float m = expf(ar);
  float Abr = m*cosf(ai), Abi = m*sinf(ai);
  int t = d*NST + n;
  Abar[2*t] = Abr; Abar[2*t+1] = Abi;
  float cr = Abr - 1.f, ci = Abi;
  float dr = Are + 1e-8f, di = Aim;
  float den = dr*dr + di*di;
  coef[2*t]   = (cr*dr + ci*di)/den;
  coef[2*t+1] = (ci*dr - cr*di)/den;
  for (int j = 0; j < LCH; ++j) {
    float p = (float)(j+1);
    float mp = expf(ar*p);
    Apow[(size_t)(t*LCH + j)*2 + 0] = mp*cosf(ai*p);
    Apow[(size_t)(t*LCH + j)*2 + 1] = mp*sinf(ai*p);
  }
  float mL = expf(ar*64.f);
  AbarL[2*t] = mL*cosf(ai*64.f); AbarL[2*t+1] = mL*sinf(ai*64.f);
}

// Bmat transposed bf16: Bmat_t[2c+p][f]
__global__ __launch_bounds__(256) void k_bmat_t(
    const float* __restrict__ Brf, const float* __restrict__ Bif,
    const float* __restrict__ Brb, const float* __restrict__ Bib,
    const float* __restrict__ coef, unsigned short* __restrict__ Bmat_t)
{
  int id = blockIdx.x*256 + threadIdx.x;     // over 128*1024
  int f = id & (NF-1), c = id >> 10;
  int d = c >> 6, n = c & 63;
  const float* Br = d ? Brb : Brf;
  const float* Bi = d ? Bib : Bif;
  float br = Br[(size_t)n*NF + f], bi = Bi[(size_t)n*NF + f];
  float crr = coef[2*c], cii = coef[2*c+1];
  Bmat_t[(size_t)(2*c)*NF + f]   = f2bf(crr*br - cii*bi);
  Bmat_t[(size_t)(2*c+1)*NF + f] = f2bf(crr*bi + cii*br);
}

// Ccat bf16 [256 r][2048 f']: sign-folded C, zero outside own direction block
__global__ __launch_bounds__(256) void k_ccat(
    const float* __restrict__ Crf, const float* __restrict__ Cif,
    const float* __restrict__ Crb, const float* __restrict__ Cib,
    unsigned short* __restrict__ Ccat)
{
  int id = blockIdx.x*256 + threadIdx.x;     // over 256*2048
  int fp = id & 2047, r = id >> 11;
  int p = r & 1, c = r >> 1, d = c >> 6, n = c & 63;
  int fd = fp >> 10, f = fp & 1023;
  float v = 0.f;
  if (fd == d) {
    const float* Cr = d ? Crb : Crf;
    const float* Ci = d ? Cib : Cif;
    v = p ? -Ci[(size_t)f*NST + n] : Cr[(size_t)f*NST + n];
  }
  Ccat[id] = f2bf(v);
}

// LayerNorm + AdaLN modulate, bf16 output into Acat region (ld = LDA)
__global__ __launch_bounds__(256) void k_ln_mod_bf(const float* __restrict__ xin, const float* __restrict__ ada,
                                                   int sh_off, int sc_off, unsigned short* __restrict__ outp) {
  const int row = blockIdx.x;
  const int b = row >> 12;
  const int tid = threadIdx.x;
  float4 v = ((const float4*)(xin + (size_t)row*NF))[tid];
  float s1 = v.x+v.y+v.z+v.w;
  float s2 = v.x*v.x + v.y*v.y + v.z*v.z + v.w*v.w;
  for (int off = 32; off > 0; off >>= 1) { s1 += __shfl_down(s1, off); s2 += __shfl_down(s2, off); }
  __shared__ float r1[4], r2[4];
  if ((tid & 63) == 0) { r1[tid>>6] = s1; r2[tid>>6] = s2; }
  __syncthreads();
  float S1 = r1[0]+r1[1]+r1[2]+r1[3];
  float S2 = r2[0]+r2[1]+r2[2]+r2[3];
  float mean = S1 * (1.0f/NF);
  float var  = S2 * (1.0f/NF) - mean*mean;
  float inv  = rsqrtf(var + 1e-5f);
  const float* arow = ada + (size_t)b*NADA;
  int f = tid << 2;
  ushort4 r;
  r.x = f2bf((v.x - mean)*inv*(1.f + arow[sc_off + f+0]) + arow[sh_off + f+0]);
  r.y = f2bf((v.y - mean)*inv*(1.f + arow[sc_off + f+1]) + arow[sh_off + f+1]);
  r.z = f2bf((v.z - mean)*inv*(1.f + arow[sc_off + f+2]) + arow[sh_off + f+2]);
  r.w = f2bf((v.w - mean)*inv*(1.f + arow[sc_off + f+3]) + arow[sh_off + f+3]);
  *(ushort4*)(outp + (size_t)row*LDA + f) = r;
}

// scan phase A: per-(b,chunk) local complex scan on fp32 bu
__global__ __launch_bounds__(128) void k_scanA(float* __restrict__ Bu, const float* __restrict__ Abar,
                                               float* __restrict__ P) {
  int t = threadIdx.x;
  int bc = blockIdx.x;
  int b = bc >> 6, c = bc & 63;
  int d = t >> 6;
  float2 A = ((const float2*)Abar)[t];
  float sr = 0.f, si = 0.f;
  size_t base = ((size_t)b*NSEQ)*(2*NCH);
  for (int j = 0; j < LCH; ++j) {
    int s = d ? (c*LCH + (LCH-1) - j) : (c*LCH + j);
    float2* p = (float2*)(Bu + base + (size_t)s*(2*NCH)) + t;
    float2 u = *p;
    float nr = A.x*sr - A.y*si + u.x;
    float ni = A.x*si + A.y*sr + u.y;
    sr = nr; si = ni;
    *p = make_float2(sr, si);
  }
  ((float2*)P)[(size_t)bc*NCH + t] = make_float2(sr, si);
}

__global__ __launch_bounds__(512) void k_scanB(const float* __restrict__ P, const float* __restrict__ AbarL,
                                               float* __restrict__ carry) {
  int t = threadIdx.x & (NCH-1);
  int b = threadIdx.x >> 7;
  int d = t >> 6;
  float2 AL = ((const float2*)AbarL)[t];
  float sr = 0.f, si = 0.f;
  if (d == 0) {
    for (int c = 0; c < NCHUNK; ++c) {
      ((float2*)carry)[((size_t)b*NCHUNK + c)*NCH + t] = make_float2(sr, si);
      float2 p = ((const float2*)P)[((size_t)b*NCHUNK + c)*NCH + t];
      float nr = AL.x*sr - AL.y*si + p.x;
      float ni = AL.x*si + AL.y*sr + p.y;
      sr = nr; si = ni;
    }
  } else {
    for (int c = NCHUNK-1; c >= 0; --c) {
      ((float2*)carry)[((size_t)b*NCHUNK + c)*NCH + t] = make_float2(sr, si);
      float2 p = ((const float2*)P)[((size_t)b*NCHUNK + c)*NCH + t];
      float nr = AL.x*sr - AL.y*si + p.x;
      float ni = AL.x*si + AL.y*sr + p.y;
      sr = nr; si = ni;
    }
  }
}

// scan phase C fused with bf16 convert: Acat cols 0..255 <- local + A^(tau+1)*carry
__global__ __launch_bounds__(128) void k_scanC(const float* __restrict__ Bu, const float* __restrict__ Apow,
                                               const float* __restrict__ carry,
                                               unsigned short* __restrict__ Acat) {
  int t = threadIdx.x;
  int bc = blockIdx.x;
  int b = bc >> 6, c = bc & 63;
  int d = t >> 6;
  float2 E = ((const float2*)carry)[(size_t)bc*NCH + t];
  const float2* Ap = ((const float2*)Apow) + (size_t)t*LCH;
  size_t base = ((size_t)b*NSEQ)*(2*NCH);
  for (int j = 0; j < LCH; ++j) {
    int s = c*LCH + j;
    int tau = d ? (LCH-1 - j) : j;
    float2 ap = Ap[tau];
    float2 v = *((const float2*)(Bu + base + (size_t)s*(2*NCH)) + t);
    v.x += ap.x*E.x - ap.y*E.y;
    v.y += ap.x*E.y + ap.y*E.x;
    ushort2 o; o.x = f2bf(v.x); o.y = f2bf(v.y);
    *(ushort2*)(Acat + (size_t)(b*NSEQ + s)*LDA + 2*t) = o;
  }
}

// tiled transpose + f32->bf16: src[R][C] -> dst[C][R] (dst leading dim ldd)
__global__ void k_tcvt(const float* __restrict__ src, int R, int C,
                       unsigned short* __restrict__ dst, int ldd) {
  __shared__ float t[32][33];
  int c0 = blockIdx.x*32, r0 = blockIdx.y*32;
  for (int rr = threadIdx.y; rr < 32; rr += 8)
    t[rr][threadIdx.x] = src[(size_t)(r0+rr)*C + c0 + threadIdx.x];
  __syncthreads();
  for (int rr = threadIdx.y; rr < 32; rr += 8)
    dst[(size_t)(c0+rr)*ldd + r0 + threadIdx.x] = f2bf(t[threadIdx.x][rr]);
}

// fused WD transpose: dst[fo][f] = bf16(Df[f]*W[f][fo] + Db[f]*W[1024+f][fo]); dst ld = LDA
__global__ void k_wd_t(const float* __restrict__ Df, const float* __restrict__ Db,
                       const float* __restrict__ W, unsigned short* __restrict__ dst) {
  __shared__ float t1[32][33], t2[32][33];
  __shared__ float df[32], db[32];
  int fo0 = blockIdx.x*32, f0 = blockIdx.y*32;
  for (int rr = threadIdx.y; rr < 32; rr += 8) {
    t1[rr][threadIdx.x] = W[(size_t)(f0+rr)*NF + fo0 + threadIdx.x];
    t2[rr][threadIdx.x] = W[(size_t)(NF+f0+rr)*NF + fo0 + threadIdx.x];
  }
  if (threadIdx.y == 0) { df[threadIdx.x] = Df[f0+threadIdx.x]; db[threadIdx.x] = Db[f0+threadIdx.x]; }
  __syncthreads();
  for (int rr = threadIdx.y; rr < 32; rr += 8)
    dst[(size_t)(fo0+rr)*LDA + f0 + threadIdx.x] =
        f2bf(df[threadIdx.x]*t1[threadIdx.x][rr] + db[threadIdx.x]*t2[threadIdx.x][rr]);
}

// ---------------- launcher ----------------
extern "C" void kernel_launch(void* const* d_in, const int* in_sizes, int n_in,
                              void* d_out, int out_size, void* d_ws, size_t ws_size,
                              hipStream_t stream) {
  const bool sig = (in_sizes[4] == 64);
  const float* x    = (const float*)d_in[0];
  const float* cond = (const float*)d_in[1];
  const float* adaW = (const float*)d_in[2];
  const float* adab = (const float*)d_in[3];
  const int fwd0 = sig ? 4 : 11;
  const int bwd0 = sig ? 12 : 19;
  const float* outW = (const float*)d_in[sig ? 20 : 4];
  const float* outb = (const float*)d_in[sig ? 21 : 5];
  const float* W1   = (const float*)d_in[sig ? 22 : 6];
  const float* b1   = (const float*)d_in[sig ? 23 : 7];
  const float* W2   = (const float*)d_in[sig ? 24 : 8];
  const float* b2   = (const float*)d_in[sig ? 25 : 9];
  const float* lAf  = (const float*)d_in[fwd0+0];
  const float* Aif  = (const float*)d_in[fwd0+1];
  const float* Brf  = (const float*)d_in[fwd0+2];
  const float* Bif  = (const float*)d_in[fwd0+3];
  const float* Crf  = (const float*)d_in[fwd0+4];
  const float* Cif  = (const float*)d_in[fwd0+5];
  const float* Df   = (const float*)d_in[fwd0+6];
  const float* ldtf = (const float*)d_in[fwd0+7];
  const float* lAb  = (const float*)d_in[bwd0+0];
  const float* Aib  = (const float*)d_in[bwd0+1];
  const float* Brb  = (const float*)d_in[bwd0+2];
  const float* Bib  = (const float*)d_in[bwd0+3];
  const float* Crb  = (const float*)d_in[bwd0+4];
  const float* Cib  = (const float*)d_in[bwd0+5];
  const float* Db   = (const float*)d_in[bwd0+6];
  const float* ldtb = (const float*)d_in[bwd0+7];
  float* out = (float*)d_out;
  (void)n_in; (void)out_size;

  char* w = (char*)d_ws;
  auto alloc = [&](size_t bytes) { char* p = w; w += (bytes + 255) & ~(size_t)255; return p; };
  unsigned short* Acat   = (unsigned short*)alloc((size_t)NROWS*LDA*2);     // 41.9 MB
  unsigned short* W1t    = (unsigned short*)alloc((size_t)NHID*NF*2);       // 8.4 MB
  unsigned short* W2t    = (unsigned short*)alloc((size_t)NF*NHID*2);       // 8.4 MB
  unsigned short* Wot    = (unsigned short*)alloc((size_t)NF*2048*2);       // 4.2 MB
  unsigned short* Ccat   = (unsigned short*)alloc((size_t)256*2048*2);      // 1.0 MB
  unsigned short* Bmat_t = (unsigned short*)alloc((size_t)2*NCH*NF*2);      // 0.5 MB
  unsigned short* Bcat   = (unsigned short*)alloc((size_t)NF*LDA*2);        // 2.6 MB
  float* bu    = (float*)alloc((size_t)NROWS*2*NCH*4);                      // 16.8 MB
  float* ada   = (float*)alloc((size_t)NB*NADA*4);
  float* part  = (float*)alloc((size_t)8*NB*NADA*4);                        // 0.8 MB
  float* sc    = (float*)alloc((size_t)NB*NF*4);
  float* Abar  = (float*)alloc(2*NCH*4);
  float* AbarL = (float*)alloc(2*NCH*4);
  float* coef  = (float*)alloc(2*NCH*4);
  float* Apow  = (float*)alloc((size_t)NCH*LCH*2*4);
  float* P     = (float*)alloc((size_t)NB*NCHUNK*NCH*2*4);
  float* carry = (float*)alloc((size_t)NB*NCHUNK*NCH*2*4);
  // mid: as big as workspace allows (16384 / 8192 / 4096 rows)
  size_t used = (size_t)(w - (char*)d_ws);
  int mrows = NROWS;
  while (mrows > 4096 && used + (size_t)mrows*NHID*2 > ws_size) mrows >>= 1;
  unsigned short* mid = (unsigned short*)alloc((size_t)mrows*NHID*2);

  // conditioning + parameter tables
  k_silu<<<(NB*NF+255)/256, 256, 0, stream>>>(cond, sc);
  k_ada1<<<dim3(NADA/256, NB, 8), 256, 0, stream>>>(sc, adaW, part);
  k_ada2<<<dim3(NADA/256, NB), 256, 0, stream>>>(part, adab, ada);
  k_param<<<2, 64, 0, stream>>>(lAf, Aif, ldtf, lAb, Aib, ldtb, Abar, coef, AbarL, Apow);
  k_bmat_t<<<(2*NCH*NF)/(2*256), 256, 0, stream>>>(Brf, Bif, Brb, Bib, coef, Bmat_t);
  k_ccat<<<(256*2048)/256, 256, 0, stream>>>(Crf, Cif, Crb, Cib, Ccat);

  // weight converts (bf16, transposed)
  k_tcvt<<<dim3(NHID/32, NF/32), dim3(32,8), 0, stream>>>(W1, NF, NHID, W1t, NF);
  k_tcvt<<<dim3(NF/32, NHID/32), dim3(32,8), 0, stream>>>(W2, NHID, NF, W2t, NHID);
  k_tcvt<<<dim3(NF/32, 2048/32), dim3(32,8), 0, stream>>>(outW, 2048, NF, Wot, 2048);

  // Bcat: G part (MFMA) + WD part (fused transpose)
  k_mm_g<<<dim3(4, NF/128), 256, 0, stream>>>(Ccat, Wot, Bcat);
  k_wd_t<<<dim3(NF/32, NF/32), dim3(32,8), 0, stream>>>(Df, Db, outW, Bcat + 256);

  // LN1 -> h (bf16) into Acat cols 256..1279
  k_ln_mod_bf<<<NROWS, 256, 0, stream>>>(x, ada, 0, NF, Acat + 256);

  // Bu GEMM (bf16 MFMA) -> fp32 bu
  k_mm_bu<<<dim3(NROWS/64, (2*NCH)/128), 256, 0, stream>>>(Acat + 256, Bmat_t, bu);

  // chunked parallel scan (fp32), phase C writes bf16 xs into Acat cols 0..255
  k_scanA<<<NB*NCHUNK, NCH, 0, stream>>>(bu, Abar, P);
  k_scanB<<<1, 512, 0, stream>>>(P, AbarL, carry);
  k_scanC<<<NB*NCHUNK, NCH, 0, stream>>>(bu, Apow, carry, Acat);

  // x1 = x + g1*(Acat @ Bcat^T + outb)
  k_mm_proj<<<dim3(NROWS/128, NF/128), 256, 0, stream>>>(Acat, Bcat, x, ada, outb, out);

  // LN2 -> h2 (bf16) into Acat cols 256..1279 (xs region dead now)
  k_ln_mod_bf<<<NROWS, 256, 0, stream>>>(out, ada, 3*NF, 4*NF, Acat + 256);

  // MLP (row-chunked only if workspace demands it)
  for (int r0 = 0; r0 < NROWS; r0 += mrows) {
    k_mm_mlp1<<<dim3(mrows/128, NHID/128), 256, 0, stream>>>(Acat + 256 + (size_t)r0*LDA, W1t, b1, mid);
    k_mm_mlp2<<<dim3(mrows/128, NF/128), 256, 0, stream>>>(mid, W2t, b2, ada, out, r0);
  }
}

// Round 5
// 785.889 us; speedup vs baseline: 7.6156x; 1.0070x over previous
//
#include <hip/hip_runtime.h>
#include <cstddef>

// ---------------- problem dims ----------------
#define NF    1024
#define NSEQ  4096
#define NB    4
#define NROWS (NB*NSEQ)      // 16384
#define NADA  6144
#define NHID  4096
#define NST   64
#define NCH   128            // dir(2) * state(64) complex channels
#define LCH   64             // scan chunk length
#define NCHUNK (NSEQ/LCH)    // 64
#define LDA   1280           // Acat leading dim (256 xs + 1024 h)

typedef __bf16 bf16x8 __attribute__((ext_vector_type(8)));
typedef float f32x4 __attribute__((ext_vector_type(4)));

__device__ __forceinline__ unsigned short f2bf(float x) {
  union { float f; unsigned int u; } v; v.f = x;
  unsigned int r = v.u + 0x7fffu + ((v.u >> 16) & 1u);
  return (unsigned short)(r >> 16);
}

// gelu(x) = 0.5x(1+tanh(u)) == x*sigmoid(2u); fast exp (v_exp_f32)
__device__ __forceinline__ float gelu_fast(float x) {
  float u2 = 1.5957691216057308f*(x + 0.044715f*x*x*x);   // 2*0.79788456*(...)
  return x / (1.f + __expf(-u2));
}

// ============ templated MFMA GEMM core =====================================
// Block tile TM x TN, wave grid WM x WN (WM*WN = 4 waves, 256 thr).
// A row-major [M][lda], Bt row-major [N][ldb]. BK=32 bf16.
// global_load_lds width=16 staging, ds_read_b128 frags, 16x16x32 MFMA.
template<int TM, int TN, int WM, int WN>
__device__ __forceinline__ void mfma_core(
    const unsigned short* __restrict__ A, int lda,
    const unsigned short* __restrict__ Bt, int ldb,
    int K, int row0, int col0, unsigned short* lds, f32x4* acc)
{
  constexpr int MI = TM/(16*WM), NJ = TN/(16*WN);
  const int tid  = threadIdx.x;
  const int wave = tid >> 6, lane = tid & 63;
  const int wm = wave % WM, wn = wave / WM;
  const int sr = lane >> 2;
  const int sc = (lane & 3) << 3;
  const int fr = lane & 15, fq = lane >> 4;
  unsigned short* sA = lds;            // [TM][32]
  unsigned short* sB = lds + TM*32;    // [TN][32]
  const unsigned short* a0 = A + (size_t)row0*lda;
  const unsigned short* b0 = Bt + (size_t)col0*ldb;
#pragma unroll 2
  for (int k0 = 0; k0 < K; k0 += 32) {
#pragma unroll
    for (int s = 0; s < TM/64; ++s) {
      int u = s*4 + wave;
      int r = u*16 + sr;
      __builtin_amdgcn_global_load_lds(
          (const __attribute__((address_space(1))) void*)(a0 + (size_t)r*lda + k0 + sc),
          (__attribute__((address_space(3))) void*)(sA + u*512), 16, 0, 0);
    }
#pragma unroll
    for (int s = 0; s < TN/64; ++s) {
      int u = s*4 + wave;
      int r = u*16 + sr;
      __builtin_amdgcn_global_load_lds(
          (const __attribute__((address_space(1))) void*)(b0 + (size_t)r*ldb + k0 + sc),
          (__attribute__((address_space(3))) void*)(sB + u*512), 16, 0, 0);
    }
    __syncthreads();
    bf16x8 af[MI], bv[NJ];
#pragma unroll
    for (int i = 0; i < MI; ++i)
      af[i] = *(const bf16x8*)(sA + (wm*(MI*16) + i*16 + fr)*32 + fq*8);
#pragma unroll
    for (int j = 0; j < NJ; ++j)
      bv[j] = *(const bf16x8*)(sB + (wn*(NJ*16) + j*16 + fr)*32 + fq*8);
#pragma unroll
    for (int i = 0; i < MI; ++i)
#pragma unroll
      for (int j = 0; j < NJ; ++j)
        acc[i*NJ+j] = __builtin_amdgcn_mfma_f32_16x16x32_bf16(af[i], bv[j], acc[i*NJ+j], 0, 0, 0);
    __syncthreads();
  }
}

#define ACC_INIT(N_) f32x4 acc[N_]; \
  _Pragma("unroll") for (int z_ = 0; z_ < N_; ++z_) acc[z_] = (f32x4){0.f,0.f,0.f,0.f};

// D mapping (m89-verified): col = n0 + (lane&15), row = m0 + (lane>>4)*4 + reg
#define EPI_LOOP(WM_, MI_, NJ_, body) \
  { const int lane = threadIdx.x & 63, wave = threadIdx.x >> 6; \
    const int wm = wave % WM_, wn = wave / WM_; \
    const int fr = lane & 15, fq = lane >> 4; \
    _Pragma("unroll") for (int i = 0; i < MI_; ++i) \
    _Pragma("unroll") for (int j = 0; j < NJ_; ++j) \
    _Pragma("unroll") for (int r = 0; r < 4; ++r) { \
      int row = row0 + wm*(MI_*16) + i*16 + fq*4 + r; \
      int col = col0 + wn*(NJ_*16) + j*16 + fr; \
      float aval = acc[i*NJ_+j][r]; \
      body; } }

// Bu GEMM: h(bf16) @ Bmat_t^T -> bu fp32 [16384][256]; 64x128 tile
__global__ __launch_bounds__(256, 4) void k_mm_bu(const unsigned short* __restrict__ A,
                                                  const unsigned short* __restrict__ Bt,
                                                  float* __restrict__ C) {
  __shared__ __align__(16) unsigned short lds[(64+128)*32];
  ACC_INIT(8)
  int row0 = blockIdx.x*64, col0 = blockIdx.y*128;
  mfma_core<64,128,1,4>(A, LDA, Bt, 1024, 1024, row0, col0, lds, acc);
  EPI_LOOP(1, 4, 2, C[(size_t)row*(2*NCH) + col] = aval; )
}

// G GEMM: Ccat[256][2048] @ Wot^T -> Bcat cols 0..255 (transposed store)
__global__ __launch_bounds__(256, 4) void k_mm_g(const unsigned short* __restrict__ A,
                                                 const unsigned short* __restrict__ Bt,
                                                 unsigned short* __restrict__ Bcat) {
  __shared__ __align__(16) unsigned short lds[(64+128)*32];
  ACC_INIT(8)
  int row0 = blockIdx.x*64, col0 = blockIdx.y*128;
  mfma_core<64,128,1,4>(A, 2048, Bt, 2048, 2048, row0, col0, lds, acc);
  EPI_LOOP(1, 4, 2, Bcat[(size_t)col*LDA + row] = f2bf(aval); )
}

// proj: out = x + g1 * (Acat@Bcat^T + outb); 128x128 tile
__global__ __launch_bounds__(256, 4) void k_mm_proj(const unsigned short* __restrict__ A,
                                                    const unsigned short* __restrict__ Bt,
                                                    const float* __restrict__ x,
                                                    const float* __restrict__ ada,
                                                    const float* __restrict__ outb,
                                                    float* __restrict__ outp) {
  __shared__ __align__(16) unsigned short lds[2*128*32];
  ACC_INIT(16)
  int row0 = blockIdx.x*128, col0 = blockIdx.y*128;
  mfma_core<128,128,2,2>(A, LDA, Bt, LDA, LDA, row0, col0, lds, acc);
  EPI_LOOP(2, 4, 4,
    const float* g1 = ada + (size_t)(row >> 12)*NADA + 2*NF;
    outp[(size_t)row*NF + col] = x[(size_t)row*NF + col] + g1[col]*(aval + outb[col]); )
}

// mlp1: mid = bf16(gelu(h2@W1t^T + b1)); 128x128 tile
__global__ __launch_bounds__(256, 4) void k_mm_mlp1(const unsigned short* __restrict__ A,
                                                    const unsigned short* __restrict__ Bt,
                                                    const float* __restrict__ b1,
                                                    unsigned short* __restrict__ mid) {
  __shared__ __align__(16) unsigned short lds[2*128*32];
  ACC_INIT(16)
  int row0 = blockIdx.x*128, col0 = blockIdx.y*128;
  mfma_core<128,128,2,2>(A, LDA, Bt, 1024, 1024, row0, col0, lds, acc);
  EPI_LOOP(2, 4, 4, mid[(size_t)row*NHID + col] = f2bf(gelu_fast(aval + b1[col])); )
}

// mlp2: out += g2 * (mid@W2t^T + b2); 128x128 tile
__global__ __launch_bounds__(256, 4) void k_mm_mlp2(const unsigned short* __restrict__ A,
                                                    const unsigned short* __restrict__ Bt,
                                                    const float* __restrict__ b2,
                                                    const float* __restrict__ ada,
                                                    float* __restrict__ outp, int row_off) {
  __shared__ __align__(16) unsigned short lds[2*128*32];
  ACC_INIT(16)
  int row0 = blockIdx.x*128, col0 = blockIdx.y*128;
  mfma_core<128,128,2,2>(A, NHID, Bt, NHID, NHID, row0, col0, lds, acc);
  EPI_LOOP(2, 4, 4,
    int rg = row_off + row;
    const float* g2 = ada + (size_t)(rg >> 12)*NADA + 5*NF;
    outp[(size_t)rg*NF + col] += g2[col]*(aval + b2[col]); )
}

// ---------------- small kernels ----------------
// ada phase 1 (silu fused): k-split partials. grid (NADA/256, NB, 8)
__global__ __launch_bounds__(256) void k_ada1(const float* __restrict__ cond, const float* __restrict__ adaW,
                                              float* __restrict__ part) {
  int j = blockIdx.x*256 + threadIdx.x;
  int b = blockIdx.y, z = blockIdx.z;
  float acc = 0.f;
  const float* s = cond + b*NF;
  int k0 = z*128;
  for (int k = k0; k < k0+128; ++k) {
    float c = s[k];
    acc += (c / (1.f + __expf(-c))) * adaW[(size_t)k*NADA + j];
  }
  part[((size_t)(z*NB + b))*NADA + j] = acc;
}

// ada phase 2: reduce 8 partials + bias. grid (NADA/256, NB)
__global__ __launch_bounds__(256) void k_ada2(const float* __restrict__ part, const float* __restrict__ adab,
                                              float* __restrict__ ada) {
  int j = blockIdx.x*256 + threadIdx.x;
  int b = blockIdx.y;
  float acc = adab[j];
#pragma unroll
  for (int z = 0; z < 8; ++z) acc += part[((size_t)(z*NB + b))*NADA + j];
  ada[(size_t)b*NADA + j] = acc;
}

__global__ __launch_bounds__(64) void k_param(
    const float* __restrict__ lAf, const float* __restrict__ Aif, const float* __restrict__ ldtf,
    const float* __restrict__ lAb, const float* __restrict__ Aib, const float* __restrict__ ldtb,
    float* __restrict__ Abar, float* __restrict__ coef, float* __restrict__ AbarL, float* __restrict__ Apow)
{
  int d = blockIdx.x, n = threadIdx.x;
  const float* lA  = d ? lAb  : lAf;
  const float* Ai  = d ? Aib  : Aif;
  const float* ldt = d ? ldtb : ldtf;
  float dt  = expf(ldt[n]);
  float Are = -expf(lA[n]);
  float Aim = Ai[n];
  float ar = Are*dt, ai = Aim*dt;
  float m = expf(ar);
  float Abr = m*cosf(ai), Abi = m*sinf(ai);
  int t = d*NST + n;
  Abar[2*t] = Abr; Abar[2*t+1] = Abi;
  float cr = Abr - 1.f, ci = Abi;
  float dr = Are + 1e-8f, di = Aim;
  float den = dr*dr + di*di;
  coef[2*t]   = (cr*dr + ci*di)/den;
  coef[2*t+1] = (ci*dr - cr*di)/den;
  for (int j = 0; j < LCH; ++j) {
    float p = (float)(j+1);
    float mp = expf(ar*p);
    Apow[(size_t)(t*LCH + j)*2 + 0] = mp*cosf(ai*p);
    Apow[(size_t)(t*LCH + j)*2 + 1] = mp*sinf(ai*p);
  }
  float mL = expf(ar*64.f);
  AbarL[2*t] = mL*cosf(ai*64.f); AbarL[2*t+1] = mL*sinf(ai*64.f);
}

// Bmat transposed bf16: Bmat_t[2c+p][f]
__global__ __launch_bounds__(256) void k_bmat_t(
    const float* __restrict__ Brf, const float* __restrict__ Bif,
    const float* __restrict__ Brb, const float* __restrict__ Bib,
    const float* __restrict__ coef, unsigned short* __restrict__ Bmat_t)
{
  int id = blockIdx.x*256 + threadIdx.x;     // over 128*1024
  int f = id & (NF-1), c = id >> 10;
  int d = c >> 6, n = c & 63;
  const float* Br = d ? Brb : Brf;
  const float* Bi = d ? Bib : Bif;
  float br = Br[(size_t)n*NF + f], bi = Bi[(size_t)n*NF + f];
  float crr = coef[2*c], cii = coef[2*c+1];
  Bmat_t[(size_t)(2*c)*NF + f]   = f2bf(crr*br - cii*bi);
  Bmat_t[(size_t)(2*c+1)*NF + f] = f2bf(crr*bi + cii*br);
}

// Ccat bf16 [256 r][2048 f']: sign-folded C, zero outside own direction block
__global__ __launch_bounds__(256) void k_ccat(
    const float* __restrict__ Crf, const float* __restrict__ Cif,
    const float* __restrict__ Crb, const float* __restrict__ Cib,
    unsigned short* __restrict__ Ccat)
{
  int id = blockIdx.x*256 + threadIdx.x;     // over 256*2048
  int fp = id & 2047, r = id >> 11;
  int p = r & 1, c = r >> 1, d = c >> 6, n = c & 63;
  int fd = fp >> 10, f = fp & 1023;
  float v = 0.f;
  if (fd == d) {
    const float* Cr = d ? Crb : Crf;
    const float* Ci = d ? Cib : Cif;
    v = p ? -Ci[(size_t)f*NST + n] : Cr[(size_t)f*NST + n];
  }
  Ccat[id] = f2bf(v);
}

// LayerNorm + AdaLN modulate, bf16 output into Acat region (ld = LDA)
__global__ __launch_bounds__(256) void k_ln_mod_bf(const float* __restrict__ xin, const float* __restrict__ ada,
                                                   int sh_off, int sc_off, unsigned short* __restrict__ outp) {
  const int row = blockIdx.x;
  const int b = row >> 12;
  const int tid = threadIdx.x;
  float4 v = ((const float4*)(xin + (size_t)row*NF))[tid];
  float s1 = v.x+v.y+v.z+v.w;
  float s2 = v.x*v.x + v.y*v.y + v.z*v.z + v.w*v.w;
  for (int off = 32; off > 0; off >>= 1) { s1 += __shfl_down(s1, off); s2 += __shfl_down(s2, off); }
  __shared__ float r1[4], r2[4];
  if ((tid & 63) == 0) { r1[tid>>6] = s1; r2[tid>>6] = s2; }
  __syncthreads();
  float S1 = r1[0]+r1[1]+r1[2]+r1[3];
  float S2 = r2[0]+r2[1]+r2[2]+r2[3];
  float mean = S1 * (1.0f/NF);
  float var  = S2 * (1.0f/NF) - mean*mean;
  float inv  = rsqrtf(var + 1e-5f);
  const float* arow = ada + (size_t)b*NADA;
  int f = tid << 2;
  ushort4 r;
  r.x = f2bf((v.x - mean)*inv*(1.f + arow[sc_off + f+0]) + arow[sh_off + f+0]);
  r.y = f2bf((v.y - mean)*inv*(1.f + arow[sc_off + f+1]) + arow[sh_off + f+1]);
  r.z = f2bf((v.z - mean)*inv*(1.f + arow[sc_off + f+2]) + arow[sh_off + f+2]);
  r.w = f2bf((v.w - mean)*inv*(1.f + arow[sc_off + f+3]) + arow[sh_off + f+3]);
  *(ushort4*)(outp + (size_t)row*LDA + f) = r;
}

// scan phase A: per-(b,chunk) local complex scan on fp32 bu
__global__ __launch_bounds__(128) void k_scanA(float* __restrict__ Bu, const float* __restrict__ Abar,
                                               float* __restrict__ P) {
  int t = threadIdx.x;
  int bc = blockIdx.x;
  int b = bc >> 6, c = bc & 63;
  int d = t >> 6;
  float2 A = ((const float2*)Abar)[t];
  float sr = 0.f, si = 0.f;
  size_t base = ((size_t)b*NSEQ)*(2*NCH);
  for (int j = 0; j < LCH; ++j) {
    int s = d ? (c*LCH + (LCH-1) - j) : (c*LCH + j);
    float2* p = (float2*)(Bu + base + (size_t)s*(2*NCH)) + t;
    float2 u = *p;
    float nr = A.x*sr - A.y*si + u.x;
    float ni = A.x*si + A.y*sr + u.y;
    sr = nr; si = ni;
    *p = make_float2(sr, si);
  }
  ((float2*)P)[(size_t)bc*NCH + t] = make_float2(sr, si);
}

__global__ __launch_bounds__(512) void k_scanB(const float* __restrict__ P, const float* __restrict__ AbarL,
                                               float* __restrict__ carry) {
  int t = threadIdx.x & (NCH-1);
  int b = threadIdx.x >> 7;
  int d = t >> 6;
  float2 AL = ((const float2*)AbarL)[t];
  float sr = 0.f, si = 0.f;
  if (d == 0) {
    for (int c = 0; c < NCHUNK; ++c) {
      ((float2*)carry)[((size_t)b*NCHUNK + c)*NCH + t] = make_float2(sr, si);
      float2 p = ((const float2*)P)[((size_t)b*NCHUNK + c)*NCH + t];
      float nr = AL.x*sr - AL.y*si + p.x;
      float ni = AL.x*si + AL.y*sr + p.y;
      sr = nr; si = ni;
    }
  } else {
    for (int c = NCHUNK-1; c >= 0; --c) {
      ((float2*)carry)[((size_t)b*NCHUNK + c)*NCH + t] = make_float2(sr, si);
      float2 p = ((const float2*)P)[((size_t)b*NCHUNK + c)*NCH + t];
      float nr = AL.x*sr - AL.y*si + p.x;
      float ni = AL.x*si + AL.y*sr + p.y;
      sr = nr; si = ni;
    }
  }
}

// scan phase C fused with bf16 convert: Acat cols 0..255 <- local + A^(tau+1)*carry
__global__ __launch_bounds__(128) void k_scanC(const float* __restrict__ Bu, const float* __restrict__ Apow,
                                               const float* __restrict__ carry,
                                               unsigned short* __restrict__ Acat) {
  int t = threadIdx.x;
  int bc = blockIdx.x;
  int b = bc >> 6, c = bc & 63;
  int d = t >> 6;
  float2 E = ((const float2*)carry)[(size_t)bc*NCH + t];
  const float2* Ap = ((const float2*)Apow) + (size_t)t*LCH;
  size_t base = ((size_t)b*NSEQ)*(2*NCH);
  for (int j = 0; j < LCH; ++j) {
    int s = c*LCH + j;
    int tau = d ? (LCH-1 - j) : j;
    float2 ap = Ap[tau];
    float2 v = *((const float2*)(Bu + base + (size_t)s*(2*NCH)) + t);
    v.x += ap.x*E.x - ap.y*E.y;
    v.y += ap.x*E.y + ap.y*E.x;
    ushort2 o; o.x = f2bf(v.x); o.y = f2bf(v.y);
    *(ushort2*)(Acat + (size_t)(b*NSEQ + s)*LDA + 2*t) = o;
  }
}

// tiled transpose + f32->bf16: src[R][C] -> dst[C][R] (dst leading dim ldd)
__global__ void k_tcvt(const float* __restrict__ src, int R, int C,
                       unsigned short* __restrict__ dst, int ldd) {
  __shared__ float t[32][33];
  int c0 = blockIdx.x*32, r0 = blockIdx.y*32;
  for (int rr = threadIdx.y; rr < 32; rr += 8)
    t[rr][threadIdx.x] = src[(size_t)(r0+rr)*C + c0 + threadIdx.x];
  __syncthreads();
  for (int rr = threadIdx.y; rr < 32; rr += 8)
    dst[(size_t)(c0+rr)*ldd + r0 + threadIdx.x] = f2bf(t[threadIdx.x][rr]);
}

// fused WD transpose: dst[fo][f] = bf16(Df[f]*W[f][fo] + Db[f]*W[1024+f][fo]); dst ld = LDA
__global__ void k_wd_t(const float* __restrict__ Df, const float* __restrict__ Db,
                       const float* __restrict__ W, unsigned short* __restrict__ dst) {
  __shared__ float t1[32][33], t2[32][33];
  __shared__ float df[32], db[32];
  int fo0 = blockIdx.x*32, f0 = blockIdx.y*32;
  for (int rr = threadIdx.y; rr < 32; rr += 8) {
    t1[rr][threadIdx.x] = W[(size_t)(f0+rr)*NF + fo0 + threadIdx.x];
    t2[rr][threadIdx.x] = W[(size_t)(NF+f0+rr)*NF + fo0 + threadIdx.x];
  }
  if (threadIdx.y == 0) { df[threadIdx.x] = Df[f0+threadIdx.x]; db[threadIdx.x] = Db[f0+threadIdx.x]; }
  __syncthreads();
  for (int rr = threadIdx.y; rr < 32; rr += 8)
    dst[(size_t)(fo0+rr)*LDA + f0 + threadIdx.x] =
        f2bf(df[threadIdx.x]*t1[threadIdx.x][rr] + db[threadIdx.x]*t2[threadIdx.x][rr]);
}

// ---------------- launcher ----------------
extern "C" void kernel_launch(void* const* d_in, const int* in_sizes, int n_in,
                              void* d_out, int out_size, void* d_ws, size_t ws_size,
                              hipStream_t stream) {
  const bool sig = (in_sizes[4] == 64);
  const float* x    = (const float*)d_in[0];
  const float* cond = (const float*)d_in[1];
  const float* adaW = (const float*)d_in[2];
  const float* adab = (const float*)d_in[3];
  const int fwd0 = sig ? 4 : 11;
  const int bwd0 = sig ? 12 : 19;
  const float* outW = (const float*)d_in[sig ? 20 : 4];
  const float* outb = (const float*)d_in[sig ? 21 : 5];
  const float* W1   = (const float*)d_in[sig ? 22 : 6];
  const float* b1   = (const float*)d_in[sig ? 23 : 7];
  const float* W2   = (const float*)d_in[sig ? 24 : 8];
  const float* b2   = (const float*)d_in[sig ? 25 : 9];
  const float* lAf  = (const float*)d_in[fwd0+0];
  const float* Aif  = (const float*)d_in[fwd0+1];
  const float* Brf  = (const float*)d_in[fwd0+2];
  const float* Bif  = (const float*)d_in[fwd0+3];
  const float* Crf  = (const float*)d_in[fwd0+4];
  const float* Cif  = (const float*)d_in[fwd0+5];
  const float* Df   = (const float*)d_in[fwd0+6];
  const float* ldtf = (const float*)d_in[fwd0+7];
  const float* lAb  = (const float*)d_in[bwd0+0];
  const float* Aib  = (const float*)d_in[bwd0+1];
  const float* Brb  = (const float*)d_in[bwd0+2];
  const float* Bib  = (const float*)d_in[bwd0+3];
  const float* Crb  = (const float*)d_in[bwd0+4];
  const float* Cib  = (const float*)d_in[bwd0+5];
  const float* Db   = (const float*)d_in[bwd0+6];
  const float* ldtb = (const float*)d_in[bwd0+7];
  float* out = (float*)d_out;
  (void)n_in; (void)out_size;

  char* w = (char*)d_ws;
  auto alloc = [&](size_t bytes) { char* p = w; w += (bytes + 255) & ~(size_t)255; return p; };
  unsigned short* Acat   = (unsigned short*)alloc((size_t)NROWS*LDA*2);     // 41.9 MB
  unsigned short* W1t    = (unsigned short*)alloc((size_t)NHID*NF*2);       // 8.4 MB
  unsigned short* W2t    = (unsigned short*)alloc((size_t)NF*NHID*2);       // 8.4 MB
  unsigned short* Wot    = (unsigned short*)alloc((size_t)NF*2048*2);       // 4.2 MB
  unsigned short* Ccat   = (unsigned short*)alloc((size_t)256*2048*2);      // 1.0 MB
  unsigned short* Bmat_t = (unsigned short*)alloc((size_t)2*NCH*NF*2);      // 0.5 MB
  unsigned short* Bcat   = (unsigned short*)alloc((size_t)NF*LDA*2);        // 2.6 MB
  float* bu    = (float*)alloc((size_t)NROWS*2*NCH*4);                      // 16.8 MB
  float* ada   = (float*)alloc((size_t)NB*NADA*4);
  float* part  = (float*)alloc((size_t)8*NB*NADA*4);                       // 0.8 MB
  float* Abar  = (float*)alloc(2*NCH*4);
  float* AbarL = (float*)alloc(2*NCH*4);
  float* coef  = (float*)alloc(2*NCH*4);
  float* Apow  = (float*)alloc((size_t)NCH*LCH*2*4);
  float* P     = (float*)alloc((size_t)NB*NCHUNK*NCH*2*4);
  float* carry = (float*)alloc((size_t)NB*NCHUNK*NCH*2*4);
  // mid: as big as workspace allows (16384 / 8192 / 4096 rows)
  size_t used = (size_t)(w - (char*)d_ws);
  int mrows = NROWS;
  while (mrows > 4096 && used + (size_t)mrows*NHID*2 > ws_size) mrows >>= 1;
  unsigned short* mid = (unsigned short*)alloc((size_t)mrows*NHID*2);

  // conditioning + parameter tables
  k_ada1<<<dim3(NADA/256, NB, 8), 256, 0, stream>>>(cond, adaW, part);
  k_ada2<<<dim3(NADA/256, NB), 256, 0, stream>>>(part, adab, ada);
  k_param<<<2, 64, 0, stream>>>(lAf, Aif, ldtf, lAb, Aib, ldtb, Abar, coef, AbarL, Apow);
  k_bmat_t<<<(2*NCH*NF)/(2*256), 256, 0, stream>>>(Brf, Bif, Brb, Bib, coef, Bmat_t);
  k_ccat<<<(256*2048)/256, 256, 0, stream>>>(Crf, Cif, Crb, Cib, Ccat);

  // weight converts (bf16, transposed)
  k_tcvt<<<dim3(NHID/32, NF/32), dim3(32,8), 0, stream>>>(W1, NF, NHID, W1t, NF);
  k_tcvt<<<dim3(NF/32, NHID/32), dim3(32,8), 0, stream>>>(W2, NHID, NF, W2t, NHID);
  k_tcvt<<<dim3(NF/32, 2048/32), dim3(32,8), 0, stream>>>(outW, 2048, NF, Wot, 2048);

  // Bcat: G part (MFMA) + WD part (fused transpose)
  k_mm_g<<<dim3(4, NF/128), 256, 0, stream>>>(Ccat, Wot, Bcat);
  k_wd_t<<<dim3(NF/32, NF/32), dim3(32,8), 0, stream>>>(Df, Db, outW, Bcat + 256);

  // LN1 -> h (bf16) into Acat cols 256..1279
  k_ln_mod_bf<<<NROWS, 256, 0, stream>>>(x, ada, 0, NF, Acat + 256);

  // Bu GEMM (bf16 MFMA) -> fp32 bu
  k_mm_bu<<<dim3(NROWS/64, (2*NCH)/128), 256, 0, stream>>>(Acat + 256, Bmat_t, bu);

  // chunked parallel scan (fp32), phase C writes bf16 xs into Acat cols 0..255
  k_scanA<<<NB*NCHUNK, NCH, 0, stream>>>(bu, Abar, P);
  k_scanB<<<1, 512, 0, stream>>>(P, AbarL, carry);
  k_scanC<<<NB*NCHUNK, NCH, 0, stream>>>(bu, Apow, carry, Acat);

  // x1 = x + g1*(Acat @ Bcat^T + outb)
  k_mm_proj<<<dim3(NROWS/128, NF/128), 256, 0, stream>>>(Acat, Bcat, x, ada, outb, out);

  // LN2 -> h2 (bf16) into Acat cols 256..1279 (xs region dead now)
  k_ln_mod_bf<<<NROWS, 256, 0, stream>>>(out, ada, 3*NF, 4*NF, Acat + 256);

  // MLP (row-chunked only if workspace demands it)
  for (int r0 = 0; r0 < NROWS; r0 += mrows) {
    k_mm_mlp1<<<dim3(mrows/128, NHID/128), 256, 0, stream>>>(Acat + 256 + (size_t)r0*LDA, W1t, b1, mid);
    k_mm_mlp2<<<dim3(mrows/128, NF/128), 256, 0, stream>>>(mid, W2t, b2, ada, out, r0);
  }
}

// Round 6
// 765.858 us; speedup vs baseline: 7.8148x; 1.0262x over previous
//
#include <hip/hip_runtime.h>
#include <cstddef>

// ---------------- problem dims ----------------
#define NF    1024
#define NSEQ  4096
#define NB    4
#define NROWS (NB*NSEQ)      // 16384
#define NADA  6144
#define NHID  4096
#define NST   64
#define NCH   128            // dir(2) * state(64) complex channels
#define LCH   64             // scan chunk length
#define NCHUNK (NSEQ/LCH)    // 64
#define LDA   1280           // Acat leading dim (256 xs + 1024 h)

typedef __bf16 bf16x8 __attribute__((ext_vector_type(8)));
typedef float f32x4 __attribute__((ext_vector_type(4)));

#define AS1 __attribute__((address_space(1)))
#define AS3 __attribute__((address_space(3)))

__device__ __forceinline__ unsigned short f2bf(float x) {
  union { float f; unsigned int u; } v; v.f = x;
  unsigned int r = v.u + 0x7fffu + ((v.u >> 16) & 1u);
  return (unsigned short)(r >> 16);
}

// gelu(x) = 0.5x(1+tanh(u)) == x*sigmoid(2u); fast exp (v_exp_f32)
__device__ __forceinline__ float gelu_fast(float x) {
  float u2 = 1.5957691216057308f*(x + 0.044715f*x*x*x);
  return x / (1.f + __expf(-u2));
}

// ============ templated MFMA GEMM core, two-panel BK=64 ====================
// Block tile TM x TN, wave grid WM x WN (4 waves, 256 thr). A row-major
// [M][lda], Bt row-major [N][ldb]. Per outer iter: stage TWO 32-K panels
// (each [T][32] — same bank pattern as m97), ONE barrier pair per 64 K.
template<int TM, int TN, int WM, int WN>
__device__ __forceinline__ void mfma_core(
    const unsigned short* __restrict__ A, int lda,
    const unsigned short* __restrict__ Bt, int ldb,
    int K, int row0, int col0, unsigned short* lds, f32x4* acc)
{
  constexpr int MI = TM/(16*WM), NJ = TN/(16*WN);
  const int tid  = threadIdx.x;
  const int wave = tid >> 6, lane = tid & 63;
  const int wm = wave % WM, wn = wave / WM;
  const int sr = lane >> 2;
  const int sc = (lane & 3) << 3;
  const int fr = lane & 15, fq = lane >> 4;
  unsigned short* sA = lds;             // 2 panels [TM][32]
  unsigned short* sB = lds + 2*TM*32;   // 2 panels [TN][32]
  const unsigned short* a0 = A + (size_t)row0*lda;
  const unsigned short* b0 = Bt + (size_t)col0*ldb;
  for (int k0 = 0; k0 < K; k0 += 64) {
#pragma unroll
    for (int p = 0; p < 2; ++p) {
      int kk = k0 + p*32;
#pragma unroll
      for (int s = 0; s < TM/64; ++s) {
        int u = s*4 + wave;
        __builtin_amdgcn_global_load_lds(
            (const AS1 void*)(a0 + (size_t)(u*16 + sr)*lda + kk + sc),
            (AS3 void*)(sA + p*TM*32 + u*512), 16, 0, 0);
      }
#pragma unroll
      for (int s = 0; s < TN/64; ++s) {
        int u = s*4 + wave;
        __builtin_amdgcn_global_load_lds(
            (const AS1 void*)(b0 + (size_t)(u*16 + sr)*ldb + kk + sc),
            (AS3 void*)(sB + p*TN*32 + u*512), 16, 0, 0);
      }
    }
    __syncthreads();
#pragma unroll
    for (int p = 0; p < 2; ++p) {
      bf16x8 af[MI], bv[NJ];
#pragma unroll
      for (int i = 0; i < MI; ++i)
        af[i] = *(const bf16x8*)(sA + p*TM*32 + (wm*(MI*16) + i*16 + fr)*32 + fq*8);
#pragma unroll
      for (int j = 0; j < NJ; ++j)
        bv[j] = *(const bf16x8*)(sB + p*TN*32 + (wn*(NJ*16) + j*16 + fr)*32 + fq*8);
#pragma unroll
      for (int i = 0; i < MI; ++i)
#pragma unroll
        for (int j = 0; j < NJ; ++j)
          acc[i*NJ+j] = __builtin_amdgcn_mfma_f32_16x16x32_bf16(af[i], bv[j], acc[i*NJ+j], 0, 0, 0);
    }
    __syncthreads();
  }
}

#define ACC_INIT(N_) f32x4 acc[N_]; \
  _Pragma("unroll") for (int z_ = 0; z_ < N_; ++z_) acc[z_] = (f32x4){0.f,0.f,0.f,0.f};

// D mapping (m89-verified): col = n0 + (lane&15), row = m0 + (lane>>4)*4 + reg
#define EPI_LOOP(WM_, MI_, NJ_, body) \
  { const int lane = threadIdx.x & 63, wave = threadIdx.x >> 6; \
    const int wm = wave % WM_, wn = wave / WM_; \
    const int fr = lane & 15, fq = lane >> 4; \
    _Pragma("unroll") for (int i = 0; i < MI_; ++i) \
    _Pragma("unroll") for (int j = 0; j < NJ_; ++j) \
    _Pragma("unroll") for (int r = 0; r < 4; ++r) { \
      int row = row0 + wm*(MI_*16) + i*16 + fq*4 + r; \
      int col = col0 + wn*(NJ_*16) + j*16 + fr; \
      float aval = acc[i*NJ_+j][r]; \
      body; } }

// Bu GEMM fused with scan phase A: 64x128 tile = exactly one scan chunk x 64
// complex channels. GEMM -> LDS -> local complex scan -> Bu (fp32) + P.
__global__ __launch_bounds__(256, 4) void k_mm_bu_scan(
    const unsigned short* __restrict__ A, const unsigned short* __restrict__ Bt,
    const float* __restrict__ Abar, float* __restrict__ Bu, float* __restrict__ P)
{
  __shared__ __align__(16) char smem[64*128*4];            // 32 KB (staging needs 24 KB)
  unsigned short* lds = (unsigned short*)smem;
  float* sbuf = (float*)smem;
  ACC_INIT(8)
  int row0 = blockIdx.x*64, col0 = blockIdx.y*128;
  mfma_core<64,128,1,4>(A, LDA, Bt, 1024, 1024, row0, col0, lds, acc);
  // acc -> sbuf[64][128] (local rows x local cols)
  { const int lane = threadIdx.x & 63, wave = threadIdx.x >> 6;
    const int fr = lane & 15, fq = lane >> 4;
#pragma unroll
    for (int i = 0; i < 4; ++i)
#pragma unroll
      for (int j = 0; j < 2; ++j)
#pragma unroll
        for (int r = 0; r < 4; ++r) {
          int rl = i*16 + fq*4 + r;
          int cl = wave*32 + j*16 + fr;
          sbuf[rl*128 + cl] = acc[i*2+j][r];
        }
  }
  __syncthreads();
  // local complex scan along the 64 rows (fwd for dir 0, bwd for dir 1)
  int tid = threadIdx.x;
  if (tid < 64) {
    int ch = (col0 >> 1) + tid;          // global complex channel
    int d = ch >> 6;
    float2 Ae = ((const float2*)Abar)[ch];
    float sr_ = 0.f, si_ = 0.f;
    for (int jj = 0; jj < LCH; ++jj) {
      int rl = d ? (LCH-1 - jj) : jj;
      float re = sbuf[rl*128 + 2*tid];
      float im = sbuf[rl*128 + 2*tid + 1];
      float nr = Ae.x*sr_ - Ae.y*si_ + re;
      float ni = Ae.x*si_ + Ae.y*sr_ + im;
      sr_ = nr; si_ = ni;
      sbuf[rl*128 + 2*tid]     = sr_;
      sbuf[rl*128 + 2*tid + 1] = si_;
    }
    int bc = row0 >> 6;                  // global chunk id (b*64 + c)
    ((float2*)P)[(size_t)bc*NCH + ch] = make_float2(sr_, si_);
  }
  __syncthreads();
  // sbuf -> Bu
  for (int e = tid; e < 64*32; e += 256) {
    int r = e >> 5, q = (e & 31) << 2;
    *(float4*)(Bu + (size_t)(row0 + r)*(2*NCH) + col0 + q) = *(float4*)(sbuf + r*128 + q);
  }
}

// G GEMM: Ccat[256][2048] @ Wot^T -> Bcat cols 0..255 (transposed store)
__global__ __launch_bounds__(256, 4) void k_mm_g(const unsigned short* __restrict__ A,
                                                 const unsigned short* __restrict__ Bt,
                                                 unsigned short* __restrict__ Bcat) {
  __shared__ __align__(16) unsigned short lds[2*(64+128)*32];
  ACC_INIT(8)
  int row0 = blockIdx.x*64, col0 = blockIdx.y*128;
  mfma_core<64,128,1,4>(A, 2048, Bt, 2048, 2048, row0, col0, lds, acc);
  EPI_LOOP(1, 4, 2, Bcat[(size_t)col*LDA + row] = f2bf(aval); )
}

// proj: out = x + g1 * (Acat@Bcat^T + outb); 128x128 tile
__global__ __launch_bounds__(256, 4) void k_mm_proj(const unsigned short* __restrict__ A,
                                                    const unsigned short* __restrict__ Bt,
                                                    const float* __restrict__ x,
                                                    const float* __restrict__ ada,
                                                    const float* __restrict__ outb,
                                                    float* __restrict__ outp) {
  __shared__ __align__(16) unsigned short lds[2*2*128*32];
  ACC_INIT(16)
  int row0 = blockIdx.x*128, col0 = blockIdx.y*128;
  mfma_core<128,128,2,2>(A, LDA, Bt, LDA, LDA, row0, col0, lds, acc);
  EPI_LOOP(2, 4, 4,
    const float* g1 = ada + (size_t)(row >> 12)*NADA + 2*NF;
    outp[(size_t)row*NF + col] = x[(size_t)row*NF + col] + g1[col]*(aval + outb[col]); )
}

// mlp1: mid = bf16(gelu(h2@W1t^T + b1)); 128x128 tile
__global__ __launch_bounds__(256, 4) void k_mm_mlp1(const unsigned short* __restrict__ A,
                                                    const unsigned short* __restrict__ Bt,
                                                    const float* __restrict__ b1,
                                                    unsigned short* __restrict__ mid) {
  __shared__ __align__(16) unsigned short lds[2*2*128*32];
  ACC_INIT(16)
  int row0 = blockIdx.x*128, col0 = blockIdx.y*128;
  mfma_core<128,128,2,2>(A, LDA, Bt, 1024, 1024, row0, col0, lds, acc);
  EPI_LOOP(2, 4, 4, mid[(size_t)row*NHID + col] = f2bf(gelu_fast(aval + b1[col])); )
}

// mlp2: out += g2 * (mid@W2t^T + b2); 128x128 tile
__global__ __launch_bounds__(256, 4) void k_mm_mlp2(const unsigned short* __restrict__ A,
                                                    const unsigned short* __restrict__ Bt,
                                                    const float* __restrict__ b2,
                                                    const float* __restrict__ ada,
                                                    float* __restrict__ outp, int row_off) {
  __shared__ __align__(16) unsigned short lds[2*2*128*32];
  ACC_INIT(16)
  int row0 = blockIdx.x*128, col0 = blockIdx.y*128;
  mfma_core<128,128,2,2>(A, NHID, Bt, NHID, NHID, row0, col0, lds, acc);
  EPI_LOOP(2, 4, 4,
    int rg = row_off + row;
    const float* g2 = ada + (size_t)(rg >> 12)*NADA + 5*NF;
    outp[(size_t)rg*NF + col] += g2[col]*(aval + b2[col]); )
}

// ---------------- small kernels ----------------
// ada phase 1 (silu fused): k-split partials. grid (NADA/256, NB, 8)
__global__ __launch_bounds__(256) void k_ada1(const float* __restrict__ cond, const float* __restrict__ adaW,
                                              float* __restrict__ part) {
  int j = blockIdx.x*256 + threadIdx.x;
  int b = blockIdx.y, z = blockIdx.z;
  float acc = 0.f;
  const float* s = cond + b*NF;
  int k0 = z*128;
  for (int k = k0; k < k0+128; ++k) {
    float c = s[k];
    acc += (c / (1.f + __expf(-c))) * adaW[(size_t)k*NADA + j];
  }
  part[((size_t)(z*NB + b))*NADA + j] = acc;
}

// ada phase 2: reduce 8 partials + bias
__global__ __launch_bounds__(256) void k_ada2(const float* __restrict__ part, const float* __restrict__ adab,
                                              float* __restrict__ ada) {
  int j = blockIdx.x*256 + threadIdx.x;
  int b = blockIdx.y;
  float acc = adab[j];
#pragma unroll
  for (int z = 0; z < 8; ++z) acc += part[((size_t)(z*NB + b))*NADA + j];
  ada[(size_t)b*NADA + j] = acc;
}

__global__ __launch_bounds__(64) void k_param(
    const float* __restrict__ lAf, const float* __restrict__ Aif, const float* __restrict__ ldtf,
    const float* __restrict__ lAb, const float* __restrict__ Aib, const float* __restrict__ ldtb,
    float* __restrict__ Abar, float* __restrict__ coef, float* __restrict__ AbarL, float* __restrict__ Apow)
{
  int d = blockIdx.x, n = threadIdx.x;
  const float* lA  = d ? lAb  : lAf;
  const float* Ai  = d ? Aib  : Aif;
  const float* ldt = d ? ldtb : ldtf;
  float dt  = expf(ldt[n]);
  float Are = -expf(lA[n]);
  float Aim = Ai[n];
  float ar = Are*dt, ai = Aim*dt;
  float m = expf(ar);
  float Abr = m*cosf(ai), Abi = m*sinf(ai);
  int t = d*NST + n;
  Abar[2*t] = Abr; Abar[2*t+1] = Abi;
  float cr = Abr - 1.f, ci = Abi;
  float dr = Are + 1e-8f, di = Aim;
  float den = dr*dr + di*di;
  coef[2*t]   = (cr*dr + ci*di)/den;
  coef[2*t+1] = (ci*dr - cr*di)/den;
  for (int j = 0; j < LCH; ++j) {
    float p = (float)(j+1);
    float mp = expf(ar*p);
    Apow[(size_t)(t*LCH + j)*2 + 0] = mp*cosf(ai*p);
    Apow[(size_t)(t*LCH + j)*2 + 1] = mp*sinf(ai*p);
  }
  float mL = expf(ar*64.f);
  AbarL[2*t] = mL*cosf(ai*64.f); AbarL[2*t+1] = mL*sinf(ai*64.f);
}

// merged: Bmat_t (blocks 0..511) + Ccat (blocks 512..2559)
__global__ __launch_bounds__(256) void k_tabs(
    const float* __restrict__ Brf, const float* __restrict__ Bif,
    const float* __restrict__ Brb, const float* __restrict__ Bib,
    const float* __restrict__ coef, unsigned short* __restrict__ Bmat_t,
    const float* __restrict__ Crf, const float* __restrict__ Cif,
    const float* __restrict__ Crb, const float* __restrict__ Cib,
    unsigned short* __restrict__ Ccat)
{
  if (blockIdx.x < 512) {
    int id = blockIdx.x*256 + threadIdx.x;   // over 128*1024
    int f = id & (NF-1), c = id >> 10;
    int d = c >> 6, n = c & 63;
    const float* Br = d ? Brb : Brf;
    const float* Bi = d ? Bib : Bif;
    float br = Br[(size_t)n*NF + f], bi = Bi[(size_t)n*NF + f];
    float crr = coef[2*c], cii = coef[2*c+1];
    Bmat_t[(size_t)(2*c)*NF + f]   = f2bf(crr*br - cii*bi);
    Bmat_t[(size_t)(2*c+1)*NF + f] = f2bf(crr*bi + cii*br);
  } else {
    int id = (blockIdx.x - 512)*256 + threadIdx.x;   // over 256*2048
    int fp = id & 2047, r = id >> 11;
    int p = r & 1, c = r >> 1, d = c >> 6, n = c & 63;
    int fd = fp >> 10, f = fp & 1023;
    float v = 0.f;
    if (fd == d) {
      const float* Cr = d ? Crb : Crf;
      const float* Ci = d ? Cib : Cif;
      v = p ? -Ci[(size_t)f*NST + n] : Cr[(size_t)f*NST + n];
    }
    Ccat[id] = f2bf(v);
  }
}

// transpose+convert tile helper (threads (32,8))
__device__ __forceinline__ void tcvt_tile(const float* __restrict__ src, int C,
                                          unsigned short* __restrict__ dst, int ldd,
                                          int r0, int c0, float* t) {
  for (int rr = threadIdx.y; rr < 32; rr += 8)
    t[rr*33 + threadIdx.x] = src[(size_t)(r0+rr)*C + c0 + threadIdx.x];
  __syncthreads();
  for (int rr = threadIdx.y; rr < 32; rr += 8)
    dst[(size_t)(c0+rr)*ldd + r0 + threadIdx.x] = f2bf(t[threadIdx.x*33 + rr]);
}

// merged weight prep: W1t | W2t | Wot | WD->Bcat (1D grid of tiles, threads (32,8))
__global__ void k_wprep(const float* __restrict__ W1, const float* __restrict__ W2,
                        const float* __restrict__ outW,
                        const float* __restrict__ Df, const float* __restrict__ Db,
                        unsigned short* __restrict__ W1t, unsigned short* __restrict__ W2t,
                        unsigned short* __restrict__ Wot, unsigned short* __restrict__ BcatWD) {
  __shared__ float t1[32*33], t2[32*33];
  __shared__ float df[32], db[32];
  int g = blockIdx.x;
  if (g < 4096) {                      // W1 [1024][4096] -> W1t [4096][1024]
    int c0 = (g & 127)*32, r0 = (g >> 7)*32;
    tcvt_tile(W1, NHID, W1t, NF, r0, c0, t1);
  } else if (g < 8192) {               // W2 [4096][1024] -> W2t [1024][4096]
    int g2 = g - 4096;
    int c0 = (g2 & 31)*32, r0 = (g2 >> 5)*32;
    tcvt_tile(W2, NF, W2t, NHID, r0, c0, t1);
  } else if (g < 10240) {              // outW [2048][1024] -> Wot [1024][2048]
    int g3 = g - 8192;
    int c0 = (g3 & 31)*32, r0 = (g3 >> 5)*32;
    tcvt_tile(outW, NF, Wot, 2048, r0, c0, t1);
  } else {                             // WD: Bcat[fo][256+f] = Df*W[f][fo]+Db*W[1024+f][fo]
    int g4 = g - 10240;
    int fo0 = (g4 & 31)*32, f0 = (g4 >> 5)*32;
    for (int rr = threadIdx.y; rr < 32; rr += 8) {
      t1[rr*33 + threadIdx.x] = outW[(size_t)(f0+rr)*NF + fo0 + threadIdx.x];
      t2[rr*33 + threadIdx.x] = outW[(size_t)(NF+f0+rr)*NF + fo0 + threadIdx.x];
    }
    if (threadIdx.y == 0) { df[threadIdx.x] = Df[f0+threadIdx.x]; db[threadIdx.x] = Db[f0+threadIdx.x]; }
    __syncthreads();
    for (int rr = threadIdx.y; rr < 32; rr += 8)
      BcatWD[(size_t)(fo0+rr)*LDA + f0 + threadIdx.x] =
          f2bf(df[threadIdx.x]*t1[threadIdx.x*33 + rr] + db[threadIdx.x]*t2[threadIdx.x*33 + rr]);
  }
}

// LayerNorm + AdaLN modulate, bf16 output into Acat region (ld = LDA)
__global__ __launch_bounds__(256) void k_ln_mod_bf(const float* __restrict__ xin, const float* __restrict__ ada,
                                                   int sh_off, int sc_off, unsigned short* __restrict__ outp) {
  const int row = blockIdx.x;
  const int b = row >> 12;
  const int tid = threadIdx.x;
  float4 v = ((const float4*)(xin + (size_t)row*NF))[tid];
  float s1 = v.x+v.y+v.z+v.w;
  float s2 = v.x*v.x + v.y*v.y + v.z*v.z + v.w*v.w;
  for (int off = 32; off > 0; off >>= 1) { s1 += __shfl_down(s1, off); s2 += __shfl_down(s2, off); }
  __shared__ float r1[4], r2[4];
  if ((tid & 63) == 0) { r1[tid>>6] = s1; r2[tid>>6] = s2; }
  __syncthreads();
  float S1 = r1[0]+r1[1]+r1[2]+r1[3];
  float S2 = r2[0]+r2[1]+r2[2]+r2[3];
  float mean = S1 * (1.0f/NF);
  float var  = S2 * (1.0f/NF) - mean*mean;
  float inv  = rsqrtf(var + 1e-5f);
  const float* arow = ada + (size_t)b*NADA;
  int f = tid << 2;
  ushort4 r;
  r.x = f2bf((v.x - mean)*inv*(1.f + arow[sc_off + f+0]) + arow[sh_off + f+0]);
  r.y = f2bf((v.y - mean)*inv*(1.f + arow[sc_off + f+1]) + arow[sh_off + f+1]);
  r.z = f2bf((v.z - mean)*inv*(1.f + arow[sc_off + f+2]) + arow[sh_off + f+2]);
  r.w = f2bf((v.w - mean)*inv*(1.f + arow[sc_off + f+3]) + arow[sh_off + f+3]);
  *(ushort4*)(outp + (size_t)row*LDA + f) = r;
}

// scan phase B: sequential combine of chunk carries
__global__ __launch_bounds__(512) void k_scanB(const float* __restrict__ P, const float* __restrict__ AbarL,
                                               float* __restrict__ carry) {
  int t = threadIdx.x & (NCH-1);
  int b = threadIdx.x >> 7;
  int d = t >> 6;
  float2 AL = ((const float2*)AbarL)[t];
  float sr = 0.f, si = 0.f;
  if (d == 0) {
    for (int c = 0; c < NCHUNK; ++c) {
      ((float2*)carry)[((size_t)b*NCHUNK + c)*NCH + t] = make_float2(sr, si);
      float2 p = ((const float2*)P)[((size_t)b*NCHUNK + c)*NCH + t];
      float nr = AL.x*sr - AL.y*si + p.x;
      float ni = AL.x*si + AL.y*sr + p.y;
      sr = nr; si = ni;
    }
  } else {
    for (int c = NCHUNK-1; c >= 0; --c) {
      ((float2*)carry)[((size_t)b*NCHUNK + c)*NCH + t] = make_float2(sr, si);
      float2 p = ((const float2*)P)[((size_t)b*NCHUNK + c)*NCH + t];
      float nr = AL.x*sr - AL.y*si + p.x;
      float ni = AL.x*si + AL.y*sr + p.y;
      sr = nr; si = ni;
    }
  }
}

// scan phase C fused with bf16 convert: Acat cols 0..255 <- local + A^(tau+1)*carry
__global__ __launch_bounds__(128) void k_scanC(const float* __restrict__ Bu, const float* __restrict__ Apow,
                                               const float* __restrict__ carry,
                                               unsigned short* __restrict__ Acat) {
  int t = threadIdx.x;
  int bc = blockIdx.x;
  int b = bc >> 6, c = bc & 63;
  int d = t >> 6;
  float2 E = ((const float2*)carry)[(size_t)bc*NCH + t];
  const float2* Ap = ((const float2*)Apow) + (size_t)t*LCH;
  size_t base = ((size_t)b*NSEQ)*(2*NCH);
  for (int j = 0; j < LCH; ++j) {
    int s = c*LCH + j;
    int tau = d ? (LCH-1 - j) : j;
    float2 ap = Ap[tau];
    float2 v = *((const float2*)(Bu + base + (size_t)s*(2*NCH)) + t);
    v.x += ap.x*E.x - ap.y*E.y;
    v.y += ap.x*E.y + ap.y*E.x;
    ushort2 o; o.x = f2bf(v.x); o.y = f2bf(v.y);
    *(ushort2*)(Acat + (size_t)(b*NSEQ + s)*LDA + 2*t) = o;
  }
}

// ---------------- launcher ----------------
extern "C" void kernel_launch(void* const* d_in, const int* in_sizes, int n_in,
                              void* d_out, int out_size, void* d_ws, size_t ws_size,
                              hipStream_t stream) {
  const bool sig = (in_sizes[4] == 64);
  const float* x    = (const float*)d_in[0];
  const float* cond = (const float*)d_in[1];
  const float* adaW = (const float*)d_in[2];
  const float* adab = (const float*)d_in[3];
  const int fwd0 = sig ? 4 : 11;
  const int bwd0 = sig ? 12 : 19;
  const float* outW = (const float*)d_in[sig ? 20 : 4];
  const float* outb = (const float*)d_in[sig ? 21 : 5];
  const float* W1   = (const float*)d_in[sig ? 22 : 6];
  const float* b1   = (const float*)d_in[sig ? 23 : 7];
  const float* W2   = (const float*)d_in[sig ? 24 : 8];
  const float* b2   = (const float*)d_in[sig ? 25 : 9];
  const float* lAf  = (const float*)d_in[fwd0+0];
  const float* Aif  = (const float*)d_in[fwd0+1];
  const float* Brf  = (const float*)d_in[fwd0+2];
  const float* Bif  = (const float*)d_in[fwd0+3];
  const float* Crf  = (const float*)d_in[fwd0+4];
  const float* Cif  = (const float*)d_in[fwd0+5];
  const float* Df   = (const float*)d_in[fwd0+6];
  const float* ldtf = (const float*)d_in[fwd0+7];
  const float* lAb  = (const float*)d_in[bwd0+0];
  const float* Aib  = (const float*)d_in[bwd0+1];
  const float* Brb  = (const float*)d_in[bwd0+2];
  const float* Bib  = (const float*)d_in[bwd0+3];
  const float* Crb  = (const float*)d_in[bwd0+4];
  const float* Cib  = (const float*)d_in[bwd0+5];
  const float* Db   = (const float*)d_in[bwd0+6];
  const float* ldtb = (const float*)d_in[bwd0+7];
  float* out = (float*)d_out;
  (void)n_in; (void)out_size;

  char* w = (char*)d_ws;
  auto alloc = [&](size_t bytes) { char* p = w; w += (bytes + 255) & ~(size_t)255; return p; };
  unsigned short* Acat   = (unsigned short*)alloc((size_t)NROWS*LDA*2);     // 41.9 MB
  unsigned short* W1t    = (unsigned short*)alloc((size_t)NHID*NF*2);       // 8.4 MB
  unsigned short* W2t    = (unsigned short*)alloc((size_t)NF*NHID*2);       // 8.4 MB
  unsigned short* Wot    = (unsigned short*)alloc((size_t)NF*2048*2);       // 4.2 MB
  unsigned short* Ccat   = (unsigned short*)alloc((size_t)256*2048*2);      // 1.0 MB
  unsigned short* Bmat_t = (unsigned short*)alloc((size_t)2*NCH*NF*2);      // 0.5 MB
  unsigned short* Bcat   = (unsigned short*)alloc((size_t)NF*LDA*2);        // 2.6 MB
  float* bu    = (float*)alloc((size_t)NROWS*2*NCH*4);                      // 16.8 MB
  float* ada   = (float*)alloc((size_t)NB*NADA*4);
  float* part  = (float*)alloc((size_t)8*NB*NADA*4);
  float* Abar  = (float*)alloc(2*NCH*4);
  float* AbarL = (float*)alloc(2*NCH*4);
  float* coef  = (float*)alloc(2*NCH*4);
  float* Apow  = (float*)alloc((size_t)NCH*LCH*2*4);
  float* P     = (float*)alloc((size_t)NB*NCHUNK*NCH*2*4);
  float* carry = (float*)alloc((size_t)NB*NCHUNK*NCH*2*4);
  // mid: as big as workspace allows (16384 / 8192 / 4096 rows)
  size_t used = (size_t)(w - (char*)d_ws);
  int mrows = NROWS;
  while (mrows > 4096 && used + (size_t)mrows*NHID*2 > ws_size) mrows >>= 1;
  unsigned short* mid = (unsigned short*)alloc((size_t)mrows*NHID*2);

  // conditioning + parameter tables
  k_ada1<<<dim3(NADA/256, NB, 8), 256, 0, stream>>>(cond, adaW, part);
  k_ada2<<<dim3(NADA/256, NB), 256, 0, stream>>>(part, adab, ada);
  k_param<<<2, 64, 0, stream>>>(lAf, Aif, ldtf, lAb, Aib, ldtb, Abar, coef, AbarL, Apow);
  k_tabs<<<2560, 256, 0, stream>>>(Brf, Bif, Brb, Bib, coef, Bmat_t, Crf, Cif, Crb, Cib, Ccat);
  k_wprep<<<11264, dim3(32,8), 0, stream>>>(W1, W2, outW, Df, Db, W1t, W2t, Wot, Bcat + 256);

  // Bcat: G part (MFMA over folded C x out_W)
  k_mm_g<<<dim3(4, NF/128), 256, 0, stream>>>(Ccat, Wot, Bcat);

  // LN1 -> h (bf16) into Acat cols 256..1279
  k_ln_mod_bf<<<NROWS, 256, 0, stream>>>(x, ada, 0, NF, Acat + 256);

  // Bu GEMM + local scan (phase A fused) -> fp32 bu + P
  k_mm_bu_scan<<<dim3(NROWS/64, (2*NCH)/128), 256, 0, stream>>>(Acat + 256, Bmat_t, Abar, bu, P);

  // carries, then apply + bf16 xs into Acat cols 0..255
  k_scanB<<<1, 512, 0, stream>>>(P, AbarL, carry);
  k_scanC<<<NB*NCHUNK, NCH, 0, stream>>>(bu, Apow, carry, Acat);

  // x1 = x + g1*(Acat @ Bcat^T + outb)
  k_mm_proj<<<dim3(NROWS/128, NF/128), 256, 0, stream>>>(Acat, Bcat, x, ada, outb, out);

  // LN2 -> h2 (bf16) into Acat cols 256..1279 (xs region dead now)
  k_ln_mod_bf<<<NROWS, 256, 0, stream>>>(out, ada, 3*NF, 4*NF, Acat + 256);

  // MLP (row-chunked only if workspace demands it)
  for (int r0 = 0; r0 < NROWS; r0 += mrows) {
    k_mm_mlp1<<<dim3(mrows/128, NHID/128), 256, 0, stream>>>(Acat + 256 + (size_t)r0*LDA, W1t, b1, mid);
    k_mm_mlp2<<<dim3(mrows/128, NF/128), 256, 0, stream>>>(mid, W2t, b2, ada, out, r0);
  }
}